// Round 1
// baseline (244.986 us; speedup 1.0000x reference)
//
#include <hip/hip_runtime.h>

#define B_  2
#define S_  2048
#define H_  1024
#define NH_ 16
#define HD_ 64
#define M_  (B_ * S_)   // 4096

typedef short  short8 __attribute__((ext_vector_type(8)));
typedef __bf16 bf16x8 __attribute__((ext_vector_type(8)));
typedef float  f32x4  __attribute__((ext_vector_type(4)));

__device__ __forceinline__ ushort f2bf(float f) {
  union { float f; unsigned u; } v; v.f = f;
  unsigned r = v.u + 0x7fffu + ((v.u >> 16) & 1u);   // RNE
  return (ushort)(r >> 16);
}
__device__ __forceinline__ float bf2f(ushort u) {
  union { unsigned u; float f; } v; v.u = ((unsigned)u) << 16;
  return v.f;
}

__device__ __forceinline__ void gload_lds16(const void* g, void* l) {
  __builtin_amdgcn_global_load_lds(
      (const __attribute__((address_space(1))) void*)g,
      (__attribute__((address_space(3))) void*)l, 16, 0, 0);
}

__device__ __forceinline__ f32x4 mfma_bf16(short8 a, short8 b, f32x4 c) {
  return __builtin_amdgcn_mfma_f32_16x16x32_bf16(
      __builtin_bit_cast(bf16x8, a), __builtin_bit_cast(bf16x8, b), c, 0, 0, 0);
}

// ---------------------------------------------------------------- convert
__global__ __launch_bounds__(256) void cvt_f2bf(const float* __restrict__ src,
                                                ushort* __restrict__ dst, int n) {
  int i = (blockIdx.x * 256 + threadIdx.x) * 4;
  if (i < n) {
    float4 v = *(const float4*)&src[i];
    ushort4 o;
    o.x = f2bf(v.x); o.y = f2bf(v.y); o.z = f2bf(v.z); o.w = f2bf(v.w);
    *(ushort4*)&dst[i] = o;
  }
}

// ---------------------------------------------------------------- rope tables
__global__ __launch_bounds__(256) void build_rope_tables(float* __restrict__ ct,
                                                         float* __restrict__ st) {
  int i = blockIdx.x * 256 + threadIdx.x;     // < S_*32
  int pos = i >> 5, d2 = i & 31;
  float invf = powf(10000.0f, -(float)d2 / 32.0f);
  float fr = (float)pos * invf;
  ct[i] = cosf(fr);
  st[i] = sinf(fr);
}

// ---------------------------------------------------------------- GEMM  C = A * B^T
// A: [Mdim][Kdim] bf16 row-major, Bm: [Ndim][Kdim] bf16 row-major.
// 128x128 tile, BK=32, 4 waves (2x2), each wave 64x64 via 4x4 frags of 16x16x32.
template <int OUT_BF16>
__global__ __launch_bounds__(256)
void gemm_bt(const ushort* __restrict__ A, const ushort* __restrict__ Bm,
             void* __restrict__ Cout, int Mdim, int Ndim, int Kdim) {
  __shared__ ushort As[128 * 32];
  __shared__ ushort Bs[128 * 32];
  int t = threadIdx.x;
  int w = t >> 6, l = t & 63;
  int m0 = blockIdx.y * 128, n0 = blockIdx.x * 128;
  int wr = (w >> 1) * 64, wc = (w & 1) * 64;
  int lrow = l & 15, lk8 = (l >> 4) * 8;
  int arow = t >> 2;            // staging row (c adds 64)
  int acol = (t & 3) * 8;       // staging col

  f32x4 acc[4][4];
#pragma unroll
  for (int mi = 0; mi < 4; ++mi)
#pragma unroll
    for (int ni = 0; ni < 4; ++ni) acc[mi][ni] = f32x4{0.f, 0.f, 0.f, 0.f};

  for (int k0 = 0; k0 < Kdim; k0 += 32) {
    __syncthreads();   // previous iteration's ds_reads done before overwrite
#pragma unroll
    for (int c = 0; c < 2; ++c) {
      gload_lds16(&A[(size_t)(m0 + arow + c * 64) * Kdim + k0 + acol],
                  &As[(c * 256 + w * 64) * 8]);
      gload_lds16(&Bm[(size_t)(n0 + arow + c * 64) * Kdim + k0 + acol],
                  &Bs[(c * 256 + w * 64) * 8]);
    }
    __syncthreads();   // vmcnt(0) drain + barrier
    short8 af[4], bfr[4];
#pragma unroll
    for (int i = 0; i < 4; ++i)
      af[i] = *(const short8*)&As[(wr + i * 16 + lrow) * 32 + lk8];
#pragma unroll
    for (int i = 0; i < 4; ++i)
      bfr[i] = *(const short8*)&Bs[(wc + i * 16 + lrow) * 32 + lk8];
#pragma unroll
    for (int mi = 0; mi < 4; ++mi)
#pragma unroll
      for (int ni = 0; ni < 4; ++ni)
        acc[mi][ni] = mfma_bf16(af[mi], bfr[ni], acc[mi][ni]);
  }

#pragma unroll
  for (int mi = 0; mi < 4; ++mi)
#pragma unroll
    for (int ni = 0; ni < 4; ++ni)
#pragma unroll
      for (int j = 0; j < 4; ++j) {
        int row = m0 + wr + mi * 16 + (l >> 4) * 4 + j;
        int col = n0 + wc + ni * 16 + lrow;
        float vv = acc[mi][ni][j];
        if (OUT_BF16)
          ((ushort*)Cout)[(size_t)row * Ndim + col] = f2bf(vv);
        else
          ((float*)Cout)[(size_t)row * Ndim + col] = vv;
      }
}

// ---------------------------------------------------------------- RoPE + scatter
// QKV: [M_][3*H_] bf16 (cols 0..1023=q, 1024..2047=k, 2048..3071=v)
// outputs qb/kb/vb: (b,h,s,d) bf16
__global__ __launch_bounds__(256)
void rope_scatter(const ushort* __restrict__ QKV, const float* __restrict__ ct,
                  const float* __restrict__ st, ushort* __restrict__ qb,
                  ushort* __restrict__ kb, ushort* __restrict__ vb) {
  int i = blockIdx.x * 256 + threadIdx.x;   // < M_*NH_*32
  int row = i >> 9;
  int rem = i & 511;
  int h = rem >> 5, d2 = rem & 31;
  int b = row >> 11, s = row & 2047;
  size_t base = (size_t)row * 3072;
  float c = ct[s * 32 + d2], sn = st[s * 32 + d2];
  size_t o = ((size_t)(b * NH_ + h) * S_ + s) * HD_;

  float x1 = bf2f(QKV[base + h * 64 + d2]);
  float x2 = bf2f(QKV[base + h * 64 + d2 + 32]);
  qb[o + d2]      = f2bf(x1 * c - x2 * sn);
  qb[o + d2 + 32] = f2bf(x2 * c + x1 * sn);

  x1 = bf2f(QKV[base + 1024 + h * 64 + d2]);
  x2 = bf2f(QKV[base + 1024 + h * 64 + d2 + 32]);
  kb[o + d2]      = f2bf(x1 * c - x2 * sn);
  kb[o + d2 + 32] = f2bf(x2 * c + x1 * sn);

  vb[o + d2]      = QKV[base + 2048 + h * 64 + d2];
  vb[o + d2 + 32] = QKV[base + 2048 + h * 64 + d2 + 32];
}

// ---------------------------------------------------------------- flash attention
// grid: (S_/64, B_*NH_); 256 thr = 4 waves; each wave owns 16 q-rows.
__global__ __launch_bounds__(256)
void flash_attn(const ushort* __restrict__ qb, const ushort* __restrict__ kb,
                const ushort* __restrict__ vb, ushort* __restrict__ ctx) {
  __shared__ ushort Qs[64 * 64];
  __shared__ ushort Ks[64 * 64];
  __shared__ ushort VTs[64 * 72];   // [dim][key], stride 72 keeps 16B align + bank spread
  __shared__ ushort Ps[64 * 72];    // [qrow][key]
  int qt = blockIdx.x, bh = blockIdx.y;
  int b = bh >> 4, h = bh & 15;
  int t = threadIdx.x, w = t >> 6, l = t & 63;
  int lrow = l & 15, lk8 = (l >> 4) * 8;
  const ushort* Q = qb + (size_t)bh * S_ * HD_;
  const ushort* K = kb + (size_t)bh * S_ * HD_;
  const ushort* V = vb + (size_t)bh * S_ * HD_;

#pragma unroll
  for (int c = 0; c < 2; ++c)
    gload_lds16(&Q[qt * 4096 + (c * 256 + t) * 8], &Qs[(c * 256 + w * 64) * 8]);
  __syncthreads();

  short8 aq[2];
#pragma unroll
  for (int ks = 0; ks < 2; ++ks)
    aq[ks] = *(const short8*)&Qs[(w * 16 + lrow) * 64 + ks * 32 + lk8];

  float m_[4], ls_[4];
  f32x4 O[4];
#pragma unroll
  for (int j = 0; j < 4; ++j) { m_[j] = -1e30f; ls_[j] = 0.f; }
#pragma unroll
  for (int nf = 0; nf < 4; ++nf) O[nf] = f32x4{0.f, 0.f, 0.f, 0.f};

  for (int kt = 0; kt <= qt; ++kt) {
    __syncthreads();   // previous iteration's consumers done
#pragma unroll
    for (int c = 0; c < 2; ++c)
      gload_lds16(&K[kt * 4096 + (c * 256 + t) * 8], &Ks[(c * 256 + w * 64) * 8]);
    {
      const ushort* Vt = &V[kt * 4096];
      int kr = t >> 2, dc = (t & 3) * 16;
      short8 v0 = *(const short8*)&Vt[kr * 64 + dc];
      short8 v1 = *(const short8*)&Vt[kr * 64 + dc + 8];
#pragma unroll
      for (int i = 0; i < 8; ++i) {
        VTs[(dc + i) * 72 + kr]     = (ushort)v0[i];
        VTs[(dc + 8 + i) * 72 + kr] = (ushort)v1[i];
      }
    }
    __syncthreads();

    // S = Q K^T
    f32x4 sc[4];
#pragma unroll
    for (int nf = 0; nf < 4; ++nf) sc[nf] = f32x4{0.f, 0.f, 0.f, 0.f};
#pragma unroll
    for (int nf = 0; nf < 4; ++nf)
#pragma unroll
      for (int ks = 0; ks < 2; ++ks) {
        short8 bk = *(const short8*)&Ks[(nf * 16 + lrow) * 64 + ks * 32 + lk8];
        sc[nf] = mfma_bf16(aq[ks], bk, sc[nf]);
      }

    // scale + causal mask + row max
    int qi = qt * 64 + w * 16 + (l >> 4) * 4;   // + j
    float mn[4];
#pragma unroll
    for (int j = 0; j < 4; ++j) mn[j] = -1e30f;
#pragma unroll
    for (int nf = 0; nf < 4; ++nf)
#pragma unroll
      for (int j = 0; j < 4; ++j) {
        float v = sc[nf][j] * 0.125f;
        int kj = kt * 64 + nf * 16 + lrow;
        if (kj > qi + j) v = -1e30f;
        sc[nf][j] = v;
        mn[j] = fmaxf(mn[j], v);
      }
#pragma unroll
    for (int off = 1; off < 16; off <<= 1)
#pragma unroll
      for (int j = 0; j < 4; ++j) mn[j] = fmaxf(mn[j], __shfl_xor(mn[j], off));

    float al[4], rs[4];
#pragma unroll
    for (int j = 0; j < 4; ++j) {
      float mnew = fmaxf(m_[j], mn[j]);
      al[j] = __expf(m_[j] - mnew);
      m_[j] = mnew;
      rs[j] = 0.f;
    }
#pragma unroll
    for (int nf = 0; nf < 4; ++nf)
#pragma unroll
      for (int j = 0; j < 4; ++j) {
        float p = __expf(sc[nf][j] - m_[j]);
        sc[nf][j] = p;
        rs[j] += p;
      }
#pragma unroll
    for (int off = 1; off < 16; off <<= 1)
#pragma unroll
      for (int j = 0; j < 4; ++j) rs[j] += __shfl_xor(rs[j], off);
#pragma unroll
    for (int j = 0; j < 4; ++j) ls_[j] = ls_[j] * al[j] + rs[j];
#pragma unroll
    for (int nf = 0; nf < 4; ++nf)
#pragma unroll
      for (int j = 0; j < 4; ++j) O[nf][j] *= al[j];

    // P -> LDS (bf16)
#pragma unroll
    for (int nf = 0; nf < 4; ++nf)
#pragma unroll
      for (int j = 0; j < 4; ++j)
        Ps[(w * 16 + (l >> 4) * 4 + j) * 72 + nf * 16 + lrow] = f2bf(sc[nf][j]);
    __syncthreads();

    // O += P V
#pragma unroll
    for (int ks = 0; ks < 2; ++ks) {
      short8 ap = *(const short8*)&Ps[(w * 16 + lrow) * 72 + ks * 32 + lk8];
#pragma unroll
      for (int nf = 0; nf < 4; ++nf) {
        short8 bv = *(const short8*)&VTs[(nf * 16 + lrow) * 72 + ks * 32 + lk8];
        O[nf] = mfma_bf16(ap, bv, O[nf]);
      }
    }
  }

#pragma unroll
  for (int nf = 0; nf < 4; ++nf)
#pragma unroll
    for (int j = 0; j < 4; ++j) {
      int srow = qt * 64 + w * 16 + (l >> 4) * 4 + j;
      float o = O[nf][j] / ls_[j];
      ctx[((size_t)b * S_ + srow) * H_ + h * 64 + nf * 16 + lrow] = f2bf(o);
    }
}

// ---------------------------------------------------------------- launch
extern "C" void kernel_launch(void* const* d_in, const int* in_sizes, int n_in,
                              void* d_out, int out_size, void* d_ws, size_t ws_size,
                              hipStream_t stream) {
  const float* x  = (const float*)d_in[0];
  const float* Wq = (const float*)d_in[1];
  const float* Wk = (const float*)d_in[2];
  const float* Wv = (const float*)d_in[3];
  const float* Wo = (const float*)d_in[4];

  char* ws = (char*)d_ws;
  size_t off = 0;
  ushort* xb   = (ushort*)(ws + off); off += (size_t)M_ * H_ * 2;        // 8 MB
  ushort* Wqkv = (ushort*)(ws + off); off += (size_t)3 * H_ * H_ * 2;    // 6 MB
  ushort* Wob  = (ushort*)(ws + off); off += (size_t)H_ * H_ * 2;        // 2 MB
  float*  ct   = (float*)(ws + off);  off += (size_t)S_ * 32 * 4;
  float*  st   = (float*)(ws + off);  off += (size_t)S_ * 32 * 4;
  ushort* QKV  = (ushort*)(ws + off); off += (size_t)M_ * 3 * H_ * 2;    // 25 MB
  ushort* qb   = (ushort*)(ws + off); off += (size_t)M_ * H_ * 2;
  ushort* kb   = (ushort*)(ws + off); off += (size_t)M_ * H_ * 2;
  ushort* vb   = (ushort*)(ws + off); off += (size_t)M_ * H_ * 2;
  ushort* ctx  = (ushort*)(ws + off); off += (size_t)M_ * H_ * 2;

  cvt_f2bf<<<M_ * H_ / 1024, 256, 0, stream>>>(x, xb, M_ * H_);
  cvt_f2bf<<<H_ * H_ / 1024, 256, 0, stream>>>(Wq, Wqkv, H_ * H_);
  cvt_f2bf<<<H_ * H_ / 1024, 256, 0, stream>>>(Wk, Wqkv + H_ * H_, H_ * H_);
  cvt_f2bf<<<H_ * H_ / 1024, 256, 0, stream>>>(Wv, Wqkv + 2 * H_ * H_, H_ * H_);
  cvt_f2bf<<<H_ * H_ / 1024, 256, 0, stream>>>(Wo, Wob, H_ * H_);
  build_rope_tables<<<S_ * 32 / 256, 256, 0, stream>>>(ct, st);

  gemm_bt<1><<<dim3(3 * H_ / 128, M_ / 128), 256, 0, stream>>>(
      xb, Wqkv, QKV, M_, 3 * H_, H_);
  rope_scatter<<<M_ * NH_ * 32 / 256, 256, 0, stream>>>(QKV, ct, st, qb, kb, vb);
  flash_attn<<<dim3(S_ / 64, B_ * NH_), 256, 0, stream>>>(qb, kb, vb, ctx);
  gemm_bt<0><<<dim3(H_ / 128, M_ / 128), 256, 0, stream>>>(
      ctx, Wob, d_out, M_, H_, H_);
}

// Round 2
// 200.004 us; speedup vs baseline: 1.2249x; 1.2249x over previous
//
#include <hip/hip_runtime.h>

#define B_  2
#define S_  2048
#define H_  1024
#define NH_ 16
#define HD_ 64
#define M_  (B_ * S_)   // 4096

typedef short  short8 __attribute__((ext_vector_type(8)));
typedef __bf16 bf16x8 __attribute__((ext_vector_type(8)));
typedef float  f32x4  __attribute__((ext_vector_type(4)));

__device__ __forceinline__ ushort f2bf(float f) {
  union { float f; unsigned u; } v; v.f = f;
  unsigned r = v.u + 0x7fffu + ((v.u >> 16) & 1u);   // RNE
  return (ushort)(r >> 16);
}
__device__ __forceinline__ float bf2f(ushort u) {
  union { unsigned u; float f; } v; v.u = ((unsigned)u) << 16;
  return v.f;
}

__device__ __forceinline__ void gload_lds16(const void* g, void* l) {
  __builtin_amdgcn_global_load_lds(
      (const __attribute__((address_space(1))) void*)g,
      (__attribute__((address_space(3))) void*)l, 16, 0, 0);
}

__device__ __forceinline__ f32x4 mfma_bf16(short8 a, short8 b, f32x4 c) {
  return __builtin_amdgcn_mfma_f32_16x16x32_bf16(
      __builtin_bit_cast(bf16x8, a), __builtin_bit_cast(bf16x8, b), c, 0, 0, 0);
}

// swizzled element offset within a [R][64]-bf16 LDS tile; c = 16B chunk (0..7)
__device__ __forceinline__ int swz(int r, int c) {
  return r * 64 + ((c ^ (r & 7)) << 3);
}

// ---------------------------------------------------------------- convert
__global__ __launch_bounds__(256) void cvt_f2bf(const float* __restrict__ src,
                                                ushort* __restrict__ dst, int n) {
  int i = (blockIdx.x * 256 + threadIdx.x) * 4;
  if (i < n) {
    float4 v = *(const float4*)&src[i];
    ushort4 o;
    o.x = f2bf(v.x); o.y = f2bf(v.y); o.z = f2bf(v.z); o.w = f2bf(v.w);
    *(ushort4*)&dst[i] = o;
  }
}

// ---------------------------------------------------------------- rope tables
__global__ __launch_bounds__(256) void build_rope_tables(float* __restrict__ ct,
                                                         float* __restrict__ st) {
  int i = blockIdx.x * 256 + threadIdx.x;     // < S_*32
  int pos = i >> 5, d2 = i & 31;
  float invf = powf(10000.0f, -(float)d2 / 32.0f);
  float fr = (float)pos * invf;
  ct[i] = cosf(fr);
  st[i] = sinf(fr);
}

// ---------------------------------------------------------------- GEMM  C = A * B^T
template <int OUT_BF16>
__global__ __launch_bounds__(256)
void gemm_bt(const ushort* __restrict__ A, const ushort* __restrict__ Bm,
             void* __restrict__ Cout, int Mdim, int Ndim, int Kdim) {
  __shared__ ushort As[128 * 32];
  __shared__ ushort Bs[128 * 32];
  int t = threadIdx.x;
  int w = t >> 6, l = t & 63;
  int m0 = blockIdx.y * 128, n0 = blockIdx.x * 128;
  int wr = (w >> 1) * 64, wc = (w & 1) * 64;
  int lrow = l & 15, lk8 = (l >> 4) * 8;
  int arow = t >> 2;
  int acol = (t & 3) * 8;

  f32x4 acc[4][4];
#pragma unroll
  for (int mi = 0; mi < 4; ++mi)
#pragma unroll
    for (int ni = 0; ni < 4; ++ni) acc[mi][ni] = f32x4{0.f, 0.f, 0.f, 0.f};

  for (int k0 = 0; k0 < Kdim; k0 += 32) {
    __syncthreads();
#pragma unroll
    for (int c = 0; c < 2; ++c) {
      gload_lds16(&A[(size_t)(m0 + arow + c * 64) * Kdim + k0 + acol],
                  &As[(c * 256 + w * 64) * 8]);
      gload_lds16(&Bm[(size_t)(n0 + arow + c * 64) * Kdim + k0 + acol],
                  &Bs[(c * 256 + w * 64) * 8]);
    }
    __syncthreads();
    short8 af[4], bfr[4];
#pragma unroll
    for (int i = 0; i < 4; ++i)
      af[i] = *(const short8*)&As[(wr + i * 16 + lrow) * 32 + lk8];
#pragma unroll
    for (int i = 0; i < 4; ++i)
      bfr[i] = *(const short8*)&Bs[(wc + i * 16 + lrow) * 32 + lk8];
#pragma unroll
    for (int mi = 0; mi < 4; ++mi)
#pragma unroll
      for (int ni = 0; ni < 4; ++ni)
        acc[mi][ni] = mfma_bf16(af[mi], bfr[ni], acc[mi][ni]);
  }

#pragma unroll
  for (int mi = 0; mi < 4; ++mi)
#pragma unroll
    for (int ni = 0; ni < 4; ++ni)
#pragma unroll
      for (int j = 0; j < 4; ++j) {
        int row = m0 + wr + mi * 16 + (l >> 4) * 4 + j;
        int col = n0 + wc + ni * 16 + lrow;
        float vv = acc[mi][ni][j];
        if (OUT_BF16)
          ((ushort*)Cout)[(size_t)row * Ndim + col] = f2bf(vv);
        else
          ((float*)Cout)[(size_t)row * Ndim + col] = vv;
      }
}

// ---------------------------------------------------------------- RoPE + scatter (q,k only)
__global__ __launch_bounds__(256)
void rope_scatter(const ushort* __restrict__ QKV, const float* __restrict__ ct,
                  const float* __restrict__ st, ushort* __restrict__ qb,
                  ushort* __restrict__ kb) {
  int i = blockIdx.x * 256 + threadIdx.x;   // < M_*NH_*32
  int row = i >> 9;
  int rem = i & 511;
  int h = rem >> 5, d2 = rem & 31;
  int b = row >> 11, s = row & 2047;
  size_t base = (size_t)row * 3072;
  float c = ct[s * 32 + d2], sn = st[s * 32 + d2];
  size_t o = ((size_t)(b * NH_ + h) * S_ + s) * HD_;

  float x1 = bf2f(QKV[base + h * 64 + d2]);
  float x2 = bf2f(QKV[base + h * 64 + d2 + 32]);
  qb[o + d2]      = f2bf(x1 * c - x2 * sn);
  qb[o + d2 + 32] = f2bf(x2 * c + x1 * sn);

  x1 = bf2f(QKV[base + 1024 + h * 64 + d2]);
  x2 = bf2f(QKV[base + 1024 + h * 64 + d2 + 32]);
  kb[o + d2]      = f2bf(x1 * c - x2 * sn);
  kb[o + d2 + 32] = f2bf(x2 * c + x1 * sn);
}

// ---------------------------------------------------------------- V transpose
// vt[bh][d][s]  <-  QKV[b*S+s][2048 + h*64 + d]
__global__ __launch_bounds__(256)
void transp_v(const ushort* __restrict__ QKV, ushort* __restrict__ vt) {
  __shared__ ushort T[64][72];
  int s0 = blockIdx.x * 64, bh = blockIdx.y;
  int b = bh >> 4, h = bh & 15;
  int t = threadIdx.x;
#pragma unroll
  for (int cc = 0; cc < 2; ++cc) {
    int slot = cc * 256 + t;
    int r = slot >> 3, c = slot & 7;   // r = s-row, c = d-chunk
    short8 v = *(const short8*)
        &QKV[(size_t)(b * S_ + s0 + r) * 3072 + 2048 + h * 64 + c * 8];
#pragma unroll
    for (int i = 0; i < 8; ++i) T[c * 8 + i][r] = (ushort)v[i];
  }
  __syncthreads();
  ushort* dst = vt + (size_t)bh * HD_ * S_;
#pragma unroll
  for (int cc = 0; cc < 2; ++cc) {
    int slot = cc * 256 + t;
    int d = slot >> 3, c = slot & 7;
    *(short8*)&dst[(size_t)d * S_ + s0 + c * 8] = *(const short8*)&T[d][c * 8];
  }
}

// ---------------------------------------------------------------- flash attention
// grid: (S_/128, B_*NH_); 256 thr = 4 waves; wave owns 32 q-rows (M_rep=2).
// K/V^T tiles double-buffered + XOR-swizzled; single barrier per kt.
__global__ __launch_bounds__(256, 3)
void flash_attn(const ushort* __restrict__ qb, const ushort* __restrict__ kb,
                const ushort* __restrict__ vt, ushort* __restrict__ ctx) {
  __shared__ ushort Ks[2][64 * 64];
  __shared__ ushort Vs[2][64 * 64];
  __shared__ ushort Ps[128 * 72];    // also Q staging region (first 8192 elems)
  int qt = (int)gridDim.x - 1 - (int)blockIdx.x;   // heavy blocks first
  int bh = blockIdx.y;
  int b = bh >> 4, h = bh & 15;
  int t = threadIdx.x, w = t >> 6, l = t & 63;
  int lrow = l & 15, g = l >> 4;
  int wrow = w * 32;
  const ushort* Q = qb + (size_t)bh * S_ * HD_;
  const ushort* K = kb + (size_t)bh * S_ * HD_;
  const ushort* V = vt + (size_t)bh * HD_ * S_;   // [64][2048]

  // prologue: stage Q (swizzled) into Ps region + K/V tile 0
#pragma unroll
  for (int cc = 0; cc < 4; ++cc) {
    int slot = cc * 256 + t;
    int r = slot >> 3, c = slot & 7;
    int cs = (c ^ (r & 7)) << 3;
    gload_lds16(&Q[(size_t)(qt * 128 + r) * 64 + cs], &Ps[slot * 8]);
  }
#pragma unroll
  for (int cc = 0; cc < 2; ++cc) {
    int slot = cc * 256 + t;
    int r = slot >> 3, c = slot & 7;
    int cs = (c ^ (r & 7)) << 3;
    gload_lds16(&K[(size_t)r * 64 + cs], &Ks[0][slot * 8]);
    gload_lds16(&V[(size_t)r * S_ + cs], &Vs[0][slot * 8]);
  }
  __syncthreads();

  short8 aq[2][2];
#pragma unroll
  for (int m = 0; m < 2; ++m)
#pragma unroll
    for (int ks = 0; ks < 2; ++ks)
      aq[m][ks] = *(const short8*)&Ps[swz(wrow + m * 16 + lrow, ks * 4 + g)];
  __syncthreads();   // Ps region now reusable for P

  float m_[2][4], ls_[2][4];
  f32x4 O[2][4];
#pragma unroll
  for (int m = 0; m < 2; ++m)
#pragma unroll
    for (int j = 0; j < 4; ++j) { m_[m][j] = -1e30f; ls_[m][j] = 0.f; }
#pragma unroll
  for (int m = 0; m < 2; ++m)
#pragma unroll
    for (int nf = 0; nf < 4; ++nf) O[m][nf] = f32x4{0.f, 0.f, 0.f, 0.f};

  int ktmax = 2 * qt + 1;
  for (int kt = 0; kt <= ktmax; ++kt) {
    const ushort* Kc = Ks[kt & 1];
    const ushort* Vc = Vs[kt & 1];
    if (kt < ktmax) {
      int nb = (kt + 1) & 1;
#pragma unroll
      for (int cc = 0; cc < 2; ++cc) {
        int slot = cc * 256 + t;
        int r = slot >> 3, c = slot & 7;
        int cs = (c ^ (r & 7)) << 3;
        gload_lds16(&K[(size_t)((kt + 1) * 64 + r) * 64 + cs], &Ks[nb][slot * 8]);
        gload_lds16(&V[(size_t)r * S_ + (kt + 1) * 64 + cs], &Vs[nb][slot * 8]);
      }
    }

    // S = Q K^T
    f32x4 sc[2][4];
#pragma unroll
    for (int m = 0; m < 2; ++m)
#pragma unroll
      for (int nf = 0; nf < 4; ++nf) sc[m][nf] = f32x4{0.f, 0.f, 0.f, 0.f};
#pragma unroll
    for (int ks = 0; ks < 2; ++ks)
#pragma unroll
      for (int nf = 0; nf < 4; ++nf) {
        short8 bk = *(const short8*)&Kc[swz(nf * 16 + lrow, ks * 4 + g)];
#pragma unroll
        for (int m = 0; m < 2; ++m)
          sc[m][nf] = mfma_bf16(aq[m][ks], bk, sc[m][nf]);
      }

    int qbase = qt * 128 + wrow;
#pragma unroll
    for (int m = 0; m < 2; ++m)
#pragma unroll
      for (int nf = 0; nf < 4; ++nf)
#pragma unroll
        for (int j = 0; j < 4; ++j) sc[m][nf][j] *= 0.125f;

    if (kt * 64 + 63 > qbase) {   // wave-uniform: mask needed
#pragma unroll
      for (int m = 0; m < 2; ++m)
#pragma unroll
        for (int nf = 0; nf < 4; ++nf) {
          int kj = kt * 64 + nf * 16 + lrow;
#pragma unroll
          for (int j = 0; j < 4; ++j) {
            int qi = qbase + m * 16 + g * 4 + j;
            if (kj > qi) sc[m][nf][j] = -1e30f;
          }
        }
    }

    float mn[2][4];
#pragma unroll
    for (int m = 0; m < 2; ++m)
#pragma unroll
      for (int j = 0; j < 4; ++j) mn[m][j] = -1e30f;
#pragma unroll
    for (int m = 0; m < 2; ++m)
#pragma unroll
      for (int nf = 0; nf < 4; ++nf)
#pragma unroll
        for (int j = 0; j < 4; ++j) mn[m][j] = fmaxf(mn[m][j], sc[m][nf][j]);
#pragma unroll
    for (int off = 1; off < 16; off <<= 1)
#pragma unroll
      for (int m = 0; m < 2; ++m)
#pragma unroll
        for (int j = 0; j < 4; ++j)
          mn[m][j] = fmaxf(mn[m][j], __shfl_xor(mn[m][j], off));

    float al[2][4], rs[2][4];
#pragma unroll
    for (int m = 0; m < 2; ++m)
#pragma unroll
      for (int j = 0; j < 4; ++j) {
        float mnew = fmaxf(m_[m][j], mn[m][j]);
        al[m][j] = __expf(m_[m][j] - mnew);
        m_[m][j] = mnew;
        rs[m][j] = 0.f;
      }
#pragma unroll
    for (int m = 0; m < 2; ++m)
#pragma unroll
      for (int nf = 0; nf < 4; ++nf)
#pragma unroll
        for (int j = 0; j < 4; ++j) {
          float p = __expf(sc[m][nf][j] - m_[m][j]);
          sc[m][nf][j] = p;
          rs[m][j] += p;
        }
#pragma unroll
    for (int off = 1; off < 16; off <<= 1)
#pragma unroll
      for (int m = 0; m < 2; ++m)
#pragma unroll
        for (int j = 0; j < 4; ++j) rs[m][j] += __shfl_xor(rs[m][j], off);
#pragma unroll
    for (int m = 0; m < 2; ++m)
#pragma unroll
      for (int j = 0; j < 4; ++j) ls_[m][j] = ls_[m][j] * al[m][j] + rs[m][j];
#pragma unroll
    for (int m = 0; m < 2; ++m)
#pragma unroll
      for (int nf = 0; nf < 4; ++nf)
#pragma unroll
        for (int j = 0; j < 4; ++j) O[m][nf][j] *= al[m][j];

    // P -> LDS (own rows only)
#pragma unroll
    for (int m = 0; m < 2; ++m)
#pragma unroll
      for (int nf = 0; nf < 4; ++nf)
#pragma unroll
        for (int j = 0; j < 4; ++j)
          Ps[(wrow + m * 16 + g * 4 + j) * 72 + nf * 16 + lrow] =
              f2bf(sc[m][nf][j]);
    __syncthreads();   // P visible; also drains staged loads for kt+1

    // O += P V
#pragma unroll
    for (int ks = 0; ks < 2; ++ks) {
      short8 ap[2];
#pragma unroll
      for (int m = 0; m < 2; ++m)
        ap[m] = *(const short8*)&Ps[(wrow + m * 16 + lrow) * 72 + ks * 32 + g * 8];
#pragma unroll
      for (int nf = 0; nf < 4; ++nf) {
        short8 bv = *(const short8*)&Vc[swz(nf * 16 + lrow, ks * 4 + g)];
#pragma unroll
        for (int m = 0; m < 2; ++m) O[m][nf] = mfma_bf16(ap[m], bv, O[m][nf]);
      }
    }
  }

#pragma unroll
  for (int m = 0; m < 2; ++m)
#pragma unroll
    for (int nf = 0; nf < 4; ++nf)
#pragma unroll
      for (int j = 0; j < 4; ++j) {
        int srow = qt * 128 + wrow + m * 16 + g * 4 + j;
        float o = O[m][nf][j] / ls_[m][j];
        ctx[((size_t)b * S_ + srow) * H_ + h * 64 + nf * 16 + lrow] = f2bf(o);
      }
}

// ---------------------------------------------------------------- launch
extern "C" void kernel_launch(void* const* d_in, const int* in_sizes, int n_in,
                              void* d_out, int out_size, void* d_ws, size_t ws_size,
                              hipStream_t stream) {
  const float* x  = (const float*)d_in[0];
  const float* Wq = (const float*)d_in[1];
  const float* Wk = (const float*)d_in[2];
  const float* Wv = (const float*)d_in[3];
  const float* Wo = (const float*)d_in[4];

  char* ws = (char*)d_ws;
  size_t off = 0;
  ushort* xb   = (ushort*)(ws + off); off += (size_t)M_ * H_ * 2;
  ushort* Wqkv = (ushort*)(ws + off); off += (size_t)3 * H_ * H_ * 2;
  ushort* Wob  = (ushort*)(ws + off); off += (size_t)H_ * H_ * 2;
  float*  ct   = (float*)(ws + off);  off += (size_t)S_ * 32 * 4;
  float*  st   = (float*)(ws + off);  off += (size_t)S_ * 32 * 4;
  ushort* QKV  = (ushort*)(ws + off); off += (size_t)M_ * 3 * H_ * 2;
  ushort* qb   = (ushort*)(ws + off); off += (size_t)M_ * H_ * 2;
  ushort* kb   = (ushort*)(ws + off); off += (size_t)M_ * H_ * 2;
  ushort* vtb  = (ushort*)(ws + off); off += (size_t)M_ * H_ * 2;
  ushort* ctx  = (ushort*)(ws + off); off += (size_t)M_ * H_ * 2;

  cvt_f2bf<<<M_ * H_ / 1024, 256, 0, stream>>>(x, xb, M_ * H_);
  cvt_f2bf<<<H_ * H_ / 1024, 256, 0, stream>>>(Wq, Wqkv, H_ * H_);
  cvt_f2bf<<<H_ * H_ / 1024, 256, 0, stream>>>(Wk, Wqkv + H_ * H_, H_ * H_);
  cvt_f2bf<<<H_ * H_ / 1024, 256, 0, stream>>>(Wv, Wqkv + 2 * H_ * H_, H_ * H_);
  cvt_f2bf<<<H_ * H_ / 1024, 256, 0, stream>>>(Wo, Wob, H_ * H_);
  build_rope_tables<<<S_ * 32 / 256, 256, 0, stream>>>(ct, st);

  gemm_bt<1><<<dim3(3 * H_ / 128, M_ / 128), 256, 0, stream>>>(
      xb, Wqkv, QKV, M_, 3 * H_, H_);
  rope_scatter<<<M_ * NH_ * 32 / 256, 256, 0, stream>>>(QKV, ct, st, qb, kb);
  transp_v<<<dim3(S_ / 64, B_ * NH_), 256, 0, stream>>>(QKV, vtb);
  flash_attn<<<dim3(S_ / 128, B_ * NH_), 256, 0, stream>>>(qb, kb, vtb, ctx);
  gemm_bt<0><<<dim3(H_ / 128, M_ / 128), 256, 0, stream>>>(
      ctx, Wob, d_out, M_, H_, H_);
}

// Round 3
// 179.457 us; speedup vs baseline: 1.3652x; 1.1145x over previous
//
#include <hip/hip_runtime.h>

#define B_  2
#define S_  2048
#define H_  1024
#define NH_ 16
#define HD_ 64
#define M_  (B_ * S_)   // 4096

typedef short  short8 __attribute__((ext_vector_type(8)));
typedef __bf16 bf16x8 __attribute__((ext_vector_type(8)));
typedef float  f32x4  __attribute__((ext_vector_type(4)));

__device__ __forceinline__ ushort f2bf(float f) {
  union { float f; unsigned u; } v; v.f = f;
  unsigned r = v.u + 0x7fffu + ((v.u >> 16) & 1u);   // RNE
  return (ushort)(r >> 16);
}
__device__ __forceinline__ float bf2f(ushort u) {
  union { unsigned u; float f; } v; v.u = ((unsigned)u) << 16;
  return v.f;
}
__device__ __forceinline__ unsigned pkbf(float lo, float hi) {
  return ((unsigned)f2bf(hi) << 16) | (unsigned)f2bf(lo);
}

__device__ __forceinline__ void gload_lds16(const void* g, void* l) {
  __builtin_amdgcn_global_load_lds(
      (const __attribute__((address_space(1))) void*)g,
      (__attribute__((address_space(3))) void*)l, 16, 0, 0);
}

__device__ __forceinline__ f32x4 mfma_bf16(short8 a, short8 b, f32x4 c) {
  return __builtin_amdgcn_mfma_f32_16x16x32_bf16(
      __builtin_bit_cast(bf16x8, a), __builtin_bit_cast(bf16x8, b), c, 0, 0, 0);
}

// swizzled element offset within a [R][64]-bf16 LDS tile; c = 16B chunk (0..7)
__device__ __forceinline__ int swz(int r, int c) {
  return r * 64 + ((c ^ (r & 7)) << 3);
}

// ---------------------------------------------------------------- convert
__global__ __launch_bounds__(256) void cvt_f2bf(const float* __restrict__ src,
                                                ushort* __restrict__ dst, int n) {
  int i = (blockIdx.x * 256 + threadIdx.x) * 4;
  if (i < n) {
    float4 v = *(const float4*)&src[i];
    ushort4 o;
    o.x = f2bf(v.x); o.y = f2bf(v.y); o.z = f2bf(v.z); o.w = f2bf(v.w);
    *(ushort4*)&dst[i] = o;
  }
}

// ---------------------------------------------------------------- rope tables
__global__ __launch_bounds__(256) void build_rope_tables(float* __restrict__ ct,
                                                         float* __restrict__ st) {
  int i = blockIdx.x * 256 + threadIdx.x;     // < S_*32
  int pos = i >> 5, d2 = i & 31;
  float invf = powf(10000.0f, -(float)d2 / 32.0f);
  float fr = (float)pos * invf;
  ct[i] = cosf(fr);
  st[i] = sinf(fr);
}

// ---------------------------------------------------------------- GEMM  C = A * B^T
template <int OUT_BF16>
__global__ __launch_bounds__(256)
void gemm_bt(const ushort* __restrict__ A, const ushort* __restrict__ Bm,
             void* __restrict__ Cout, int Mdim, int Ndim, int Kdim) {
  __shared__ ushort As[128 * 32];
  __shared__ ushort Bs[128 * 32];
  int t = threadIdx.x;
  int w = t >> 6, l = t & 63;
  int m0 = blockIdx.y * 128, n0 = blockIdx.x * 128;
  int wr = (w >> 1) * 64, wc = (w & 1) * 64;
  int lrow = l & 15, lk8 = (l >> 4) * 8;
  int arow = t >> 2;
  int acol = (t & 3) * 8;

  f32x4 acc[4][4];
#pragma unroll
  for (int mi = 0; mi < 4; ++mi)
#pragma unroll
    for (int ni = 0; ni < 4; ++ni) acc[mi][ni] = f32x4{0.f, 0.f, 0.f, 0.f};

  for (int k0 = 0; k0 < Kdim; k0 += 32) {
    __syncthreads();
#pragma unroll
    for (int c = 0; c < 2; ++c) {
      gload_lds16(&A[(size_t)(m0 + arow + c * 64) * Kdim + k0 + acol],
                  &As[(c * 256 + w * 64) * 8]);
      gload_lds16(&Bm[(size_t)(n0 + arow + c * 64) * Kdim + k0 + acol],
                  &Bs[(c * 256 + w * 64) * 8]);
    }
    __syncthreads();
    short8 af[4], bfr[4];
#pragma unroll
    for (int i = 0; i < 4; ++i)
      af[i] = *(const short8*)&As[(wr + i * 16 + lrow) * 32 + lk8];
#pragma unroll
    for (int i = 0; i < 4; ++i)
      bfr[i] = *(const short8*)&Bs[(wc + i * 16 + lrow) * 32 + lk8];
#pragma unroll
    for (int mi = 0; mi < 4; ++mi)
#pragma unroll
      for (int ni = 0; ni < 4; ++ni)
        acc[mi][ni] = mfma_bf16(af[mi], bfr[ni], acc[mi][ni]);
  }

#pragma unroll
  for (int mi = 0; mi < 4; ++mi)
#pragma unroll
    for (int ni = 0; ni < 4; ++ni)
#pragma unroll
      for (int j = 0; j < 4; ++j) {
        int row = m0 + wr + mi * 16 + (l >> 4) * 4 + j;
        int col = n0 + wc + ni * 16 + lrow;
        float vv = acc[mi][ni][j];
        if (OUT_BF16)
          ((ushort*)Cout)[(size_t)row * Ndim + col] = f2bf(vv);
        else
          ((float*)Cout)[(size_t)row * Ndim + col] = vv;
      }
}

// ---------------------------------------------------------------- RoPE + scatter (q,k)
// q additionally pre-scaled by 0.125*log2(e) so flash can use exp2.
__global__ __launch_bounds__(256)
void rope_scatter(const ushort* __restrict__ QKV, const float* __restrict__ ct,
                  const float* __restrict__ st, ushort* __restrict__ qb,
                  ushort* __restrict__ kb) {
  const float SC = 0.125f * 1.44269504f;
  int i = blockIdx.x * 256 + threadIdx.x;   // < M_*NH_*32
  int row = i >> 9;
  int rem = i & 511;
  int h = rem >> 5, d2 = rem & 31;
  int b = row >> 11, s = row & 2047;
  size_t base = (size_t)row * 3072;
  float c = ct[s * 32 + d2], sn = st[s * 32 + d2];
  size_t o = ((size_t)(b * NH_ + h) * S_ + s) * HD_;

  float x1 = bf2f(QKV[base + h * 64 + d2]);
  float x2 = bf2f(QKV[base + h * 64 + d2 + 32]);
  qb[o + d2]      = f2bf((x1 * c - x2 * sn) * SC);
  qb[o + d2 + 32] = f2bf((x2 * c + x1 * sn) * SC);

  x1 = bf2f(QKV[base + 1024 + h * 64 + d2]);
  x2 = bf2f(QKV[base + 1024 + h * 64 + d2 + 32]);
  kb[o + d2]      = f2bf(x1 * c - x2 * sn);
  kb[o + d2 + 32] = f2bf(x2 * c + x1 * sn);
}

// ---------------------------------------------------------------- V transpose
__global__ __launch_bounds__(256)
void transp_v(const ushort* __restrict__ QKV, ushort* __restrict__ vt) {
  __shared__ ushort T[64][72];
  int s0 = blockIdx.x * 64, bh = blockIdx.y;
  int b = bh >> 4, h = bh & 15;
  int t = threadIdx.x;
#pragma unroll
  for (int cc = 0; cc < 2; ++cc) {
    int slot = cc * 256 + t;
    int r = slot >> 3, c = slot & 7;
    short8 v = *(const short8*)
        &QKV[(size_t)(b * S_ + s0 + r) * 3072 + 2048 + h * 64 + c * 8];
#pragma unroll
    for (int i = 0; i < 8; ++i) T[c * 8 + i][r] = (ushort)v[i];
  }
  __syncthreads();
  ushort* dst = vt + (size_t)bh * HD_ * S_;
#pragma unroll
  for (int cc = 0; cc < 2; ++cc) {
    int slot = cc * 256 + t;
    int d = slot >> 3, c = slot & 7;
    *(short8*)&dst[(size_t)d * S_ + s0 + c * 8] = *(const short8*)&T[d][c * 8];
  }
}

// ---------------------------------------------------------------- flash attention v3
// Swapped-operand form: S^T = mfma(K,Q), O^T = mfma(V^T,P).
// Lane-local softmax rows (q = lane&15), 2 shuffles per reduce, packed P/out.
__global__ __launch_bounds__(256, 3)
void flash_attn(const ushort* __restrict__ qb, const ushort* __restrict__ kb,
                const ushort* __restrict__ vt, ushort* __restrict__ ctx) {
  __shared__ ushort Ks[2][64 * 64];
  __shared__ ushort Vs[2][64 * 64];
  __shared__ ushort Ps[128 * 72];    // also Q staging region
  int qt = (int)gridDim.x - 1 - (int)blockIdx.x;   // heavy blocks first
  int bh = blockIdx.y;
  int b = bh >> 4, h = bh & 15;
  int t = threadIdx.x, w = t >> 6, l = t & 63;
  int lrow = l & 15, g = l >> 4;
  int wrow = w * 32;
  const ushort* Q = qb + (size_t)bh * S_ * HD_;
  const ushort* K = kb + (size_t)bh * S_ * HD_;
  const ushort* V = vt + (size_t)bh * HD_ * S_;   // [64][2048]

  // prologue: stage Q (swizzled) into Ps region + K/V tile 0
#pragma unroll
  for (int cc = 0; cc < 4; ++cc) {
    int slot = cc * 256 + t;
    int r = slot >> 3, c = slot & 7;
    int cs = (c ^ (r & 7)) << 3;
    gload_lds16(&Q[(size_t)(qt * 128 + r) * 64 + cs], &Ps[slot * 8]);
  }
#pragma unroll
  for (int cc = 0; cc < 2; ++cc) {
    int slot = cc * 256 + t;
    int r = slot >> 3, c = slot & 7;
    int cs = (c ^ (r & 7)) << 3;
    gload_lds16(&K[(size_t)r * 64 + cs], &Ks[0][slot * 8]);
    gload_lds16(&V[(size_t)r * S_ + cs], &Vs[0][slot * 8]);
  }
  __syncthreads();

  short8 aq[2][2];
#pragma unroll
  for (int m = 0; m < 2; ++m)
#pragma unroll
    for (int ks = 0; ks < 2; ++ks)
      aq[m][ks] = *(const short8*)&Ps[swz(wrow + m * 16 + lrow, ks * 4 + g)];
  __syncthreads();   // Ps region now reusable for P

  float m_[2] = {-1e30f, -1e30f}, ls_[2] = {0.f, 0.f};
  f32x4 O[2][4];
#pragma unroll
  for (int m = 0; m < 2; ++m)
#pragma unroll
    for (int nf = 0; nf < 4; ++nf) O[m][nf] = f32x4{0.f, 0.f, 0.f, 0.f};

  int ktmax = 2 * qt + 1;
  for (int kt = 0; kt <= ktmax; ++kt) {
    const ushort* Kc = Ks[kt & 1];
    const ushort* Vc = Vs[kt & 1];
    if (kt < ktmax) {
      int nb = (kt + 1) & 1;
#pragma unroll
      for (int cc = 0; cc < 2; ++cc) {
        int slot = cc * 256 + t;
        int r = slot >> 3, c = slot & 7;
        int cs = (c ^ (r & 7)) << 3;
        gload_lds16(&K[(size_t)((kt + 1) * 64 + r) * 64 + cs], &Ks[nb][slot * 8]);
        gload_lds16(&V[(size_t)r * S_ + (kt + 1) * 64 + cs], &Vs[nb][slot * 8]);
      }
    }

    // S^T = K Q^T : lane holds q-row (lrow), k = nf*16 + g*4 + j
    f32x4 sc[2][4];
#pragma unroll
    for (int m = 0; m < 2; ++m)
#pragma unroll
      for (int nf = 0; nf < 4; ++nf) sc[m][nf] = f32x4{0.f, 0.f, 0.f, 0.f};
    __builtin_amdgcn_s_setprio(1);
#pragma unroll
    for (int ks = 0; ks < 2; ++ks)
#pragma unroll
      for (int nf = 0; nf < 4; ++nf) {
        short8 bk = *(const short8*)&Kc[swz(nf * 16 + lrow, ks * 4 + g)];
#pragma unroll
        for (int m = 0; m < 2; ++m)
          sc[m][nf] = mfma_bf16(bk, aq[m][ks], sc[m][nf]);
      }
    __builtin_amdgcn_s_setprio(0);

    int qbase = qt * 128 + wrow;
    if (kt * 64 + 63 > qbase) {   // wave-uniform: mask needed
#pragma unroll
      for (int m = 0; m < 2; ++m) {
        int qi = qbase + m * 16 + lrow;
#pragma unroll
        for (int nf = 0; nf < 4; ++nf) {
          int kbase = kt * 64 + nf * 16 + g * 4;
#pragma unroll
          for (int j = 0; j < 4; ++j)
            if (kbase + j > qi) sc[m][nf][j] = -1e30f;
        }
      }
    }

    // row max per m: in-register tree + 2 shuffles
    float mx[2];
#pragma unroll
    for (int m = 0; m < 2; ++m) {
      float a0 = fmaxf(fmaxf(sc[m][0][0], sc[m][0][1]),
                       fmaxf(sc[m][0][2], sc[m][0][3]));
      float a1 = fmaxf(fmaxf(sc[m][1][0], sc[m][1][1]),
                       fmaxf(sc[m][1][2], sc[m][1][3]));
      float a2 = fmaxf(fmaxf(sc[m][2][0], sc[m][2][1]),
                       fmaxf(sc[m][2][2], sc[m][2][3]));
      float a3 = fmaxf(fmaxf(sc[m][3][0], sc[m][3][1]),
                       fmaxf(sc[m][3][2], sc[m][3][3]));
      float a = fmaxf(fmaxf(a0, a1), fmaxf(a2, a3));
      a = fmaxf(a, __shfl_xor(a, 16));
      a = fmaxf(a, __shfl_xor(a, 32));
      mx[m] = a;
    }

    // defer-max (T13): skip rescale when max grew little
    bool nor = __all((mx[0] <= m_[0] + 8.f) && (mx[1] <= m_[1] + 8.f));
    if (!nor) {
#pragma unroll
      for (int m = 0; m < 2; ++m) {
        float mnew = fmaxf(m_[m], mx[m]);
        float al = exp2f(m_[m] - mnew);
        m_[m] = mnew;
        ls_[m] *= al;
#pragma unroll
        for (int nf = 0; nf < 4; ++nf)
#pragma unroll
          for (int j = 0; j < 4; ++j) O[m][nf][j] *= al;
      }
    }

    // exp2 + row sum + packed P write (wave-local rows)
#pragma unroll
    for (int m = 0; m < 2; ++m) {
      float rs = 0.f;
#pragma unroll
      for (int nf = 0; nf < 4; ++nf)
#pragma unroll
        for (int j = 0; j < 4; ++j) {
          float p = exp2f(sc[m][nf][j] - m_[m]);
          sc[m][nf][j] = p;
          rs += p;
        }
      rs += __shfl_xor(rs, 16);
      rs += __shfl_xor(rs, 32);
      ls_[m] += rs;
#pragma unroll
      for (int nf = 0; nf < 4; ++nf) {
        uint2 pk;
        pk.x = pkbf(sc[m][nf][0], sc[m][nf][1]);
        pk.y = pkbf(sc[m][nf][2], sc[m][nf][3]);
        *(uint2*)&Ps[(wrow + m * 16 + lrow) * 72 + nf * 16 + g * 4] = pk;
      }
    }

    // O^T += V^T P^T (wave-local P read; lgkmcnt ordering by compiler)
    __builtin_amdgcn_s_setprio(1);
#pragma unroll
    for (int ks = 0; ks < 2; ++ks) {
      short8 ap[2];
#pragma unroll
      for (int m = 0; m < 2; ++m)
        ap[m] = *(const short8*)&Ps[(wrow + m * 16 + lrow) * 72 + ks * 32 + g * 8];
#pragma unroll
      for (int nf = 0; nf < 4; ++nf) {
        short8 bv = *(const short8*)&Vc[swz(nf * 16 + lrow, ks * 4 + g)];
#pragma unroll
        for (int m = 0; m < 2; ++m) O[m][nf] = mfma_bf16(bv, ap[m], O[m][nf]);
      }
    }
    __builtin_amdgcn_s_setprio(0);

    __syncthreads();   // K/V dbuf ready for kt+1; all waves done with cur
  }

  // epilogue: O^T lane holds q = lrow, d = nf*16 + g*4 + j  -> packed stores
#pragma unroll
  for (int m = 0; m < 2; ++m) {
    float inv = 1.f / ls_[m];
    int srow = qt * 128 + wrow + m * 16 + lrow;
#pragma unroll
    for (int nf = 0; nf < 4; ++nf) {
      uint2 pk;
      pk.x = pkbf(O[m][nf][0] * inv, O[m][nf][1] * inv);
      pk.y = pkbf(O[m][nf][2] * inv, O[m][nf][3] * inv);
      *(uint2*)&ctx[((size_t)b * S_ + srow) * H_ + h * 64 + nf * 16 + g * 4] = pk;
    }
  }
}

// ---------------------------------------------------------------- launch
extern "C" void kernel_launch(void* const* d_in, const int* in_sizes, int n_in,
                              void* d_out, int out_size, void* d_ws, size_t ws_size,
                              hipStream_t stream) {
  const float* x  = (const float*)d_in[0];
  const float* Wq = (const float*)d_in[1];
  const float* Wk = (const float*)d_in[2];
  const float* Wv = (const float*)d_in[3];
  const float* Wo = (const float*)d_in[4];

  char* ws = (char*)d_ws;
  size_t off = 0;
  ushort* xb   = (ushort*)(ws + off); off += (size_t)M_ * H_ * 2;
  ushort* Wqkv = (ushort*)(ws + off); off += (size_t)3 * H_ * H_ * 2;
  ushort* Wob  = (ushort*)(ws + off); off += (size_t)H_ * H_ * 2;
  float*  ct   = (float*)(ws + off);  off += (size_t)S_ * 32 * 4;
  float*  st   = (float*)(ws + off);  off += (size_t)S_ * 32 * 4;
  ushort* QKV  = (ushort*)(ws + off); off += (size_t)M_ * 3 * H_ * 2;
  ushort* qb   = (ushort*)(ws + off); off += (size_t)M_ * H_ * 2;
  ushort* kb   = (ushort*)(ws + off); off += (size_t)M_ * H_ * 2;
  ushort* vtb  = (ushort*)(ws + off); off += (size_t)M_ * H_ * 2;
  ushort* ctx  = (ushort*)(ws + off); off += (size_t)M_ * H_ * 2;

  cvt_f2bf<<<M_ * H_ / 1024, 256, 0, stream>>>(x, xb, M_ * H_);
  cvt_f2bf<<<H_ * H_ / 1024, 256, 0, stream>>>(Wq, Wqkv, H_ * H_);
  cvt_f2bf<<<H_ * H_ / 1024, 256, 0, stream>>>(Wk, Wqkv + H_ * H_, H_ * H_);
  cvt_f2bf<<<H_ * H_ / 1024, 256, 0, stream>>>(Wv, Wqkv + 2 * H_ * H_, H_ * H_);
  cvt_f2bf<<<H_ * H_ / 1024, 256, 0, stream>>>(Wo, Wob, H_ * H_);
  build_rope_tables<<<S_ * 32 / 256, 256, 0, stream>>>(ct, st);

  gemm_bt<1><<<dim3(3 * H_ / 128, M_ / 128), 256, 0, stream>>>(
      xb, Wqkv, QKV, M_, 3 * H_, H_);
  rope_scatter<<<M_ * NH_ * 32 / 256, 256, 0, stream>>>(QKV, ct, st, qb, kb);
  transp_v<<<dim3(S_ / 64, B_ * NH_), 256, 0, stream>>>(QKV, vtb);
  flash_attn<<<dim3(S_ / 128, B_ * NH_), 256, 0, stream>>>(qb, kb, vtb, ctx);
  gemm_bt<0><<<dim3(H_ / 128, M_ / 128), 256, 0, stream>>>(
      ctx, Wob, d_out, M_, H_, H_);
}

// Round 6
// 168.582 us; speedup vs baseline: 1.4532x; 1.0645x over previous
//
#include <hip/hip_runtime.h>

#define B_  2
#define S_  2048
#define H_  1024
#define NH_ 16
#define HD_ 64
#define M_  (B_ * S_)   // 4096

typedef short  short8  __attribute__((ext_vector_type(8)));
typedef __bf16 bf16x8  __attribute__((ext_vector_type(8)));
typedef float  f32x4   __attribute__((ext_vector_type(4)));

__device__ __forceinline__ ushort f2bf(float f) {
  union { float f; unsigned u; } v; v.f = f;
  unsigned r = v.u + 0x7fffu + ((v.u >> 16) & 1u);   // RNE
  return (ushort)(r >> 16);
}
__device__ __forceinline__ float bf2f(ushort u) {
  union { unsigned u; float f; } v; v.u = ((unsigned)u) << 16;
  return v.f;
}
// packed bf16 pair via HW cvt (RNE): dst.lo=bf16(lo), dst.hi=bf16(hi)
__device__ __forceinline__ unsigned cvtpk(float lo, float hi) {
  unsigned r;
  asm("v_cvt_pk_bf16_f32 %0, %1, %2" : "=v"(r) : "v"(lo), "v"(hi));
  return r;
}

__device__ __forceinline__ void gload_lds16(const void* g, void* l) {
  __builtin_amdgcn_global_load_lds(
      (const __attribute__((address_space(1))) void*)g,
      (__attribute__((address_space(3))) void*)l, 16, 0, 0);
}

__device__ __forceinline__ f32x4 mfma_bf16(short8 a, short8 b, f32x4 c) {
  return __builtin_amdgcn_mfma_f32_16x16x32_bf16(
      __builtin_bit_cast(bf16x8, a), __builtin_bit_cast(bf16x8, b), c, 0, 0, 0);
}

// swizzled element offset within a [R][64]-bf16 LDS tile; c = 16B chunk (0..7)
__device__ __forceinline__ int swz(int r, int c) {
  return r * 64 + ((c ^ (r & 7)) << 3);
}

// ---------------------------------------------------------------- convert
__global__ __launch_bounds__(256) void cvt_f2bf(const float* __restrict__ src,
                                                ushort* __restrict__ dst, int n) {
  int i = (blockIdx.x * 256 + threadIdx.x) * 4;
  if (i < n) {
    float4 v = *(const float4*)&src[i];
    ushort4 o;
    o.x = f2bf(v.x); o.y = f2bf(v.y); o.z = f2bf(v.z); o.w = f2bf(v.w);
    *(ushort4*)&dst[i] = o;
  }
}

// all four weight matrices in one launch
__global__ __launch_bounds__(256)
void cvt_w(const float* __restrict__ Wq, const float* __restrict__ Wk,
           const float* __restrict__ Wv, const float* __restrict__ Wo,
           ushort* __restrict__ Wqkv, ushort* __restrict__ Wob) {
  int y = blockIdx.y;
  const float* src = (y == 0) ? Wq : (y == 1) ? Wk : (y == 2) ? Wv : Wo;
  ushort* dst = (y == 3) ? Wob : Wqkv + (size_t)y * H_ * H_;
  int i = (blockIdx.x * 256 + threadIdx.x) * 4;
  float4 v = *(const float4*)&src[i];
  ushort4 o;
  o.x = f2bf(v.x); o.y = f2bf(v.y); o.z = f2bf(v.z); o.w = f2bf(v.w);
  *(ushort4*)&dst[i] = o;
}

// ---------------------------------------------------------------- rope tables
__global__ __launch_bounds__(256) void build_rope_tables(float* __restrict__ ct,
                                                         float* __restrict__ st) {
  int i = blockIdx.x * 256 + threadIdx.x;     // < S_*32
  int pos = i >> 5, d2 = i & 31;
  float invf = powf(10000.0f, -(float)d2 / 32.0f);
  float fr = (float)pos * invf;
  ct[i] = cosf(fr);
  st[i] = sinf(fr);
}

// ---------------------------------------------------------------- GEMM  C = A * B^T
template <int OUT_BF16>
__global__ __launch_bounds__(256)
void gemm_bt(const ushort* __restrict__ A, const ushort* __restrict__ Bm,
             void* __restrict__ Cout, int Mdim, int Ndim, int Kdim) {
  __shared__ ushort As[128 * 32];
  __shared__ ushort Bs[128 * 32];
  int t = threadIdx.x;
  int w = t >> 6, l = t & 63;
  int m0 = blockIdx.y * 128, n0 = blockIdx.x * 128;
  int wr = (w >> 1) * 64, wc = (w & 1) * 64;
  int lrow = l & 15, lk8 = (l >> 4) * 8;
  int arow = t >> 2;
  int acol = (t & 3) * 8;

  f32x4 acc[4][4];
#pragma unroll
  for (int mi = 0; mi < 4; ++mi)
#pragma unroll
    for (int ni = 0; ni < 4; ++ni) acc[mi][ni] = f32x4{0.f, 0.f, 0.f, 0.f};

  for (int k0 = 0; k0 < Kdim; k0 += 32) {
    __syncthreads();
#pragma unroll
    for (int c = 0; c < 2; ++c) {
      gload_lds16(&A[(size_t)(m0 + arow + c * 64) * Kdim + k0 + acol],
                  &As[(c * 256 + w * 64) * 8]);
      gload_lds16(&Bm[(size_t)(n0 + arow + c * 64) * Kdim + k0 + acol],
                  &Bs[(c * 256 + w * 64) * 8]);
    }
    __syncthreads();
    short8 af[4], bfr[4];
#pragma unroll
    for (int i = 0; i < 4; ++i)
      af[i] = *(const short8*)&As[(wr + i * 16 + lrow) * 32 + lk8];
#pragma unroll
    for (int i = 0; i < 4; ++i)
      bfr[i] = *(const short8*)&Bs[(wc + i * 16 + lrow) * 32 + lk8];
#pragma unroll
    for (int mi = 0; mi < 4; ++mi)
#pragma unroll
      for (int ni = 0; ni < 4; ++ni)
        acc[mi][ni] = mfma_bf16(af[mi], bfr[ni], acc[mi][ni]);
  }

#pragma unroll
  for (int mi = 0; mi < 4; ++mi)
#pragma unroll
    for (int ni = 0; ni < 4; ++ni)
#pragma unroll
      for (int j = 0; j < 4; ++j) {
        int row = m0 + wr + mi * 16 + (l >> 4) * 4 + j;
        int col = n0 + wc + ni * 16 + lrow;
        float vv = acc[mi][ni][j];
        if (OUT_BF16)
          ((ushort*)Cout)[(size_t)row * Ndim + col] = f2bf(vv);
        else
          ((float*)Cout)[(size_t)row * Ndim + col] = vv;
      }
}

// ---------------------------------------------------------------- RoPE + scatter (q,k)
// q pre-scaled by 0.125*log2(e) so flash can use exp2.
__global__ __launch_bounds__(256)
void rope_scatter(const ushort* __restrict__ QKV, const float* __restrict__ ct,
                  const float* __restrict__ st, ushort* __restrict__ qb,
                  ushort* __restrict__ kb) {
  const float SC = 0.125f * 1.44269504f;
  int i = blockIdx.x * 256 + threadIdx.x;   // < M_*NH_*32
  int row = i >> 9;
  int rem = i & 511;
  int h = rem >> 5, d2 = rem & 31;
  int b = row >> 11, s = row & 2047;
  size_t base = (size_t)row * 3072;
  float c = ct[s * 32 + d2], sn = st[s * 32 + d2];
  size_t o = ((size_t)(b * NH_ + h) * S_ + s) * HD_;

  float x1 = bf2f(QKV[base + h * 64 + d2]);
  float x2 = bf2f(QKV[base + h * 64 + d2 + 32]);
  qb[o + d2]      = f2bf((x1 * c - x2 * sn) * SC);
  qb[o + d2 + 32] = f2bf((x2 * c + x1 * sn) * SC);

  x1 = bf2f(QKV[base + 1024 + h * 64 + d2]);
  x2 = bf2f(QKV[base + 1024 + h * 64 + d2 + 32]);
  kb[o + d2]      = f2bf(x1 * c - x2 * sn);
  kb[o + d2 + 32] = f2bf(x2 * c + x1 * sn);
}

// ---------------------------------------------------------------- V transpose
__global__ __launch_bounds__(256)
void transp_v(const ushort* __restrict__ QKV, ushort* __restrict__ vt) {
  __shared__ ushort T[64][72];
  int s0 = blockIdx.x * 64, bh = blockIdx.y;
  int b = bh >> 4, h = bh & 15;
  int t = threadIdx.x;
#pragma unroll
  for (int cc = 0; cc < 2; ++cc) {
    int slot = cc * 256 + t;
    int r = slot >> 3, c = slot & 7;
    short8 v = *(const short8*)
        &QKV[(size_t)(b * S_ + s0 + r) * 3072 + 2048 + h * 64 + c * 8];
#pragma unroll
    for (int i = 0; i < 8; ++i) T[c * 8 + i][r] = (ushort)v[i];
  }
  __syncthreads();
  ushort* dst = vt + (size_t)bh * HD_ * S_;
#pragma unroll
  for (int cc = 0; cc < 2; ++cc) {
    int slot = cc * 256 + t;
    int d = slot >> 3, c = slot & 7;
    *(short8*)&dst[(size_t)d * S_ + s0 + c * 8] = *(const short8*)&T[d][c * 8];
  }
}

// ---------------------------------------------------------------- flash attention v3c
// R3-passing structure (KVBLK=64, shfl_xor reduces) + cvt_pk packing only.
__global__ __launch_bounds__(256, 3)
void flash_attn(const ushort* __restrict__ qb, const ushort* __restrict__ kb,
                const ushort* __restrict__ vt, ushort* __restrict__ ctx) {
  __shared__ ushort Ks[2][64 * 64];
  __shared__ ushort Vs[2][64 * 64];
  __shared__ ushort Ps[128 * 72];    // also Q staging region
  int qt = (int)gridDim.x - 1 - (int)blockIdx.x;   // heavy blocks first
  int bh = blockIdx.y;
  int b = bh >> 4, h = bh & 15;
  int t = threadIdx.x, w = t >> 6, l = t & 63;
  int lrow = l & 15, g = l >> 4;
  int wrow = w * 32;
  const ushort* Q = qb + (size_t)bh * S_ * HD_;
  const ushort* K = kb + (size_t)bh * S_ * HD_;
  const ushort* V = vt + (size_t)bh * HD_ * S_;   // [64][2048]

  // prologue: stage Q (swizzled) into Ps region + K/V tile 0
#pragma unroll
  for (int cc = 0; cc < 4; ++cc) {
    int slot = cc * 256 + t;
    int r = slot >> 3, c = slot & 7;
    int cs = (c ^ (r & 7)) << 3;
    gload_lds16(&Q[(size_t)(qt * 128 + r) * 64 + cs], &Ps[slot * 8]);
  }
#pragma unroll
  for (int cc = 0; cc < 2; ++cc) {
    int slot = cc * 256 + t;
    int r = slot >> 3, c = slot & 7;
    int cs = (c ^ (r & 7)) << 3;
    gload_lds16(&K[(size_t)r * 64 + cs], &Ks[0][slot * 8]);
    gload_lds16(&V[(size_t)r * S_ + cs], &Vs[0][slot * 8]);
  }
  __syncthreads();

  short8 aq[2][2];
#pragma unroll
  for (int m = 0; m < 2; ++m)
#pragma unroll
    for (int ks = 0; ks < 2; ++ks)
      aq[m][ks] = *(const short8*)&Ps[swz(wrow + m * 16 + lrow, ks * 4 + g)];
  __syncthreads();   // Ps region now reusable for P

  float m_[2] = {-1e30f, -1e30f}, ls_[2] = {0.f, 0.f};
  f32x4 O[2][4];
#pragma unroll
  for (int m = 0; m < 2; ++m)
#pragma unroll
    for (int nf = 0; nf < 4; ++nf) O[m][nf] = f32x4{0.f, 0.f, 0.f, 0.f};

  int ktmax = 2 * qt + 1;
  for (int kt = 0; kt <= ktmax; ++kt) {
    const ushort* Kc = Ks[kt & 1];
    const ushort* Vc = Vs[kt & 1];
    if (kt < ktmax) {
      int nb = (kt + 1) & 1;
#pragma unroll
      for (int cc = 0; cc < 2; ++cc) {
        int slot = cc * 256 + t;
        int r = slot >> 3, c = slot & 7;
        int cs = (c ^ (r & 7)) << 3;
        gload_lds16(&K[(size_t)((kt + 1) * 64 + r) * 64 + cs], &Ks[nb][slot * 8]);
        gload_lds16(&V[(size_t)r * S_ + (kt + 1) * 64 + cs], &Vs[nb][slot * 8]);
      }
    }

    // S^T = K Q^T : lane holds q-row (lrow), k = nf*16 + g*4 + j
    f32x4 sc[2][4];
#pragma unroll
    for (int m = 0; m < 2; ++m)
#pragma unroll
      for (int nf = 0; nf < 4; ++nf) sc[m][nf] = f32x4{0.f, 0.f, 0.f, 0.f};
    __builtin_amdgcn_s_setprio(1);
#pragma unroll
    for (int ks = 0; ks < 2; ++ks)
#pragma unroll
      for (int nf = 0; nf < 4; ++nf) {
        short8 bk = *(const short8*)&Kc[swz(nf * 16 + lrow, ks * 4 + g)];
#pragma unroll
        for (int m = 0; m < 2; ++m)
          sc[m][nf] = mfma_bf16(bk, aq[m][ks], sc[m][nf]);
      }
    __builtin_amdgcn_s_setprio(0);

    int qbase = qt * 128 + wrow;
    if (kt * 64 + 63 > qbase) {   // wave-uniform: mask needed
#pragma unroll
      for (int m = 0; m < 2; ++m) {
        int qi = qbase + m * 16 + lrow;
#pragma unroll
        for (int nf = 0; nf < 4; ++nf) {
          int kbase = kt * 64 + nf * 16 + g * 4;
#pragma unroll
          for (int j = 0; j < 4; ++j)
            if (kbase + j > qi) sc[m][nf][j] = -1e30f;
        }
      }
    }

    // row max per m: in-register tree + 2 shuffles (known-good)
    float mx[2];
#pragma unroll
    for (int m = 0; m < 2; ++m) {
      float a0 = fmaxf(fmaxf(sc[m][0][0], sc[m][0][1]),
                       fmaxf(sc[m][0][2], sc[m][0][3]));
      float a1 = fmaxf(fmaxf(sc[m][1][0], sc[m][1][1]),
                       fmaxf(sc[m][1][2], sc[m][1][3]));
      float a2 = fmaxf(fmaxf(sc[m][2][0], sc[m][2][1]),
                       fmaxf(sc[m][2][2], sc[m][2][3]));
      float a3 = fmaxf(fmaxf(sc[m][3][0], sc[m][3][1]),
                       fmaxf(sc[m][3][2], sc[m][3][3]));
      float a = fmaxf(fmaxf(a0, a1), fmaxf(a2, a3));
      a = fmaxf(a, __shfl_xor(a, 16));
      a = fmaxf(a, __shfl_xor(a, 32));
      mx[m] = a;
    }

    // defer-max (T13): skip rescale when max grew little
    bool nor = __all((mx[0] <= m_[0] + 8.f) && (mx[1] <= m_[1] + 8.f));
    if (!nor) {
#pragma unroll
      for (int m = 0; m < 2; ++m) {
        float mnew = fmaxf(m_[m], mx[m]);
        float al = exp2f(m_[m] - mnew);
        m_[m] = mnew;
        ls_[m] *= al;
#pragma unroll
        for (int nf = 0; nf < 4; ++nf)
#pragma unroll
          for (int j = 0; j < 4; ++j) O[m][nf][j] *= al;
      }
    }

    // exp2 + row sum + packed P write (wave-local rows)
#pragma unroll
    for (int m = 0; m < 2; ++m) {
      float rs = 0.f;
#pragma unroll
      for (int nf = 0; nf < 4; ++nf)
#pragma unroll
        for (int j = 0; j < 4; ++j) {
          float p = exp2f(sc[m][nf][j] - m_[m]);
          sc[m][nf][j] = p;
          rs += p;
        }
      rs += __shfl_xor(rs, 16);
      rs += __shfl_xor(rs, 32);
      ls_[m] += rs;
#pragma unroll
      for (int nf = 0; nf < 4; ++nf) {
        uint2 pk;
        pk.x = cvtpk(sc[m][nf][0], sc[m][nf][1]);
        pk.y = cvtpk(sc[m][nf][2], sc[m][nf][3]);
        *(uint2*)&Ps[(wrow + m * 16 + lrow) * 72 + nf * 16 + g * 4] = pk;
      }
    }

    // O^T += V^T P^T (wave-local P read)
    __builtin_amdgcn_s_setprio(1);
#pragma unroll
    for (int ks = 0; ks < 2; ++ks) {
      short8 ap[2];
#pragma unroll
      for (int m = 0; m < 2; ++m)
        ap[m] = *(const short8*)&Ps[(wrow + m * 16 + lrow) * 72 + ks * 32 + g * 8];
#pragma unroll
      for (int nf = 0; nf < 4; ++nf) {
        short8 bv = *(const short8*)&Vc[swz(nf * 16 + lrow, ks * 4 + g)];
#pragma unroll
        for (int m = 0; m < 2; ++m) O[m][nf] = mfma_bf16(bv, ap[m], O[m][nf]);
      }
    }
    __builtin_amdgcn_s_setprio(0);

    __syncthreads();   // K/V dbuf ready for kt+1; all waves done with cur
  }

  // epilogue: lane q = lrow, d = nf*16 + g*4 + j -> packed stores
#pragma unroll
  for (int m = 0; m < 2; ++m) {
    float inv = 1.f / ls_[m];
    int srow = qt * 128 + wrow + m * 16 + lrow;
#pragma unroll
    for (int nf = 0; nf < 4; ++nf) {
      uint2 pk;
      pk.x = cvtpk(O[m][nf][0] * inv, O[m][nf][1] * inv);
      pk.y = cvtpk(O[m][nf][2] * inv, O[m][nf][3] * inv);
      *(uint2*)&ctx[((size_t)b * S_ + srow) * H_ + h * 64 + nf * 16 + g * 4] = pk;
    }
  }
}

// ---------------------------------------------------------------- launch
extern "C" void kernel_launch(void* const* d_in, const int* in_sizes, int n_in,
                              void* d_out, int out_size, void* d_ws, size_t ws_size,
                              hipStream_t stream) {
  const float* x  = (const float*)d_in[0];
  const float* Wq = (const float*)d_in[1];
  const float* Wk = (const float*)d_in[2];
  const float* Wv = (const float*)d_in[3];
  const float* Wo = (const float*)d_in[4];

  char* ws = (char*)d_ws;
  size_t off = 0;
  ushort* xb   = (ushort*)(ws + off); off += (size_t)M_ * H_ * 2;
  ushort* Wqkv = (ushort*)(ws + off); off += (size_t)3 * H_ * H_ * 2;
  ushort* Wob  = (ushort*)(ws + off); off += (size_t)H_ * H_ * 2;
  float*  ct   = (float*)(ws + off);  off += (size_t)S_ * 32 * 4;
  float*  st   = (float*)(ws + off);  off += (size_t)S_ * 32 * 4;
  ushort* QKV  = (ushort*)(ws + off); off += (size_t)M_ * 3 * H_ * 2;
  ushort* qb   = (ushort*)(ws + off); off += (size_t)M_ * H_ * 2;
  ushort* kb   = (ushort*)(ws + off); off += (size_t)M_ * H_ * 2;
  ushort* vtb  = (ushort*)(ws + off); off += (size_t)M_ * H_ * 2;
  ushort* ctx  = (ushort*)(ws + off); off += (size_t)M_ * H_ * 2;

  cvt_f2bf<<<M_ * H_ / 1024, 256, 0, stream>>>(x, xb, M_ * H_);
  cvt_w<<<dim3(H_ * H_ / 1024, 4), 256, 0, stream>>>(Wq, Wk, Wv, Wo, Wqkv, Wob);
  build_rope_tables<<<S_ * 32 / 256, 256, 0, stream>>>(ct, st);

  gemm_bt<1><<<dim3(3 * H_ / 128, M_ / 128), 256, 0, stream>>>(
      xb, Wqkv, QKV, M_, 3 * H_, H_);
  rope_scatter<<<M_ * NH_ * 32 / 256, 256, 0, stream>>>(QKV, ct, st, qb, kb);
  transp_v<<<dim3(S_ / 64, B_ * NH_), 256, 0, stream>>>(QKV, vtb);
  flash_attn<<<dim3(S_ / 128, B_ * NH_), 256, 0, stream>>>(qb, kb, vtb, ctx);
  gemm_bt<0><<<dim3(H_ / 128, M_ / 128), 256, 0, stream>>>(
      ctx, Wob, d_out, M_, H_, H_);
}

// Round 7
// 157.939 us; speedup vs baseline: 1.5511x; 1.0674x over previous
//
#include <hip/hip_runtime.h>

#define B_  2
#define S_  2048
#define H_  1024
#define NH_ 16
#define HD_ 64
#define M_  (B_ * S_)   // 4096

typedef short  short8  __attribute__((ext_vector_type(8)));
typedef __bf16 bf16x8  __attribute__((ext_vector_type(8)));
typedef float  f32x4   __attribute__((ext_vector_type(4)));

__device__ __forceinline__ ushort f2bf(float f) {
  union { float f; unsigned u; } v; v.f = f;
  unsigned r = v.u + 0x7fffu + ((v.u >> 16) & 1u);   // RNE
  return (ushort)(r >> 16);
}
__device__ __forceinline__ float bf2f(ushort u) {
  union { unsigned u; float f; } v; v.u = ((unsigned)u) << 16;
  return v.f;
}
// packed bf16 pair via HW cvt (RNE): dst.lo=bf16(lo), dst.hi=bf16(hi)
__device__ __forceinline__ unsigned cvtpk(float lo, float hi) {
  unsigned r;
  asm("v_cvt_pk_bf16_f32 %0, %1, %2" : "=v"(r) : "v"(lo), "v"(hi));
  return r;
}

__device__ __forceinline__ void gload_lds16(const void* g, void* l) {
  __builtin_amdgcn_global_load_lds(
      (const __attribute__((address_space(1))) void*)g,
      (__attribute__((address_space(3))) void*)l, 16, 0, 0);
}

__device__ __forceinline__ f32x4 mfma_bf16(short8 a, short8 b, f32x4 c) {
  return __builtin_amdgcn_mfma_f32_16x16x32_bf16(
      __builtin_bit_cast(bf16x8, a), __builtin_bit_cast(bf16x8, b), c, 0, 0, 0);
}

// swizzled element offsets; c = 16B chunk index
__device__ __forceinline__ int swzK(int r, int c) {   // [R][64] tiles
  return r * 64 + ((c ^ (r & 7)) << 3);
}
__device__ __forceinline__ int swzV(int r, int c) {   // [R][128] tiles
  return r * 128 + ((c ^ (r & 7)) << 3);
}

// ---------------------------------------------------------------- convert
__global__ __launch_bounds__(256) void cvt_f2bf(const float* __restrict__ src,
                                                ushort* __restrict__ dst, int n) {
  int i = (blockIdx.x * 256 + threadIdx.x) * 4;
  if (i < n) {
    float4 v = *(const float4*)&src[i];
    ushort4 o;
    o.x = f2bf(v.x); o.y = f2bf(v.y); o.z = f2bf(v.z); o.w = f2bf(v.w);
    *(ushort4*)&dst[i] = o;
  }
}

// all four weight matrices in one launch
__global__ __launch_bounds__(256)
void cvt_w(const float* __restrict__ Wq, const float* __restrict__ Wk,
           const float* __restrict__ Wv, const float* __restrict__ Wo,
           ushort* __restrict__ Wqkv, ushort* __restrict__ Wob) {
  int y = blockIdx.y;
  const float* src = (y == 0) ? Wq : (y == 1) ? Wk : (y == 2) ? Wv : Wo;
  ushort* dst = (y == 3) ? Wob : Wqkv + (size_t)y * H_ * H_;
  int i = (blockIdx.x * 256 + threadIdx.x) * 4;
  float4 v = *(const float4*)&src[i];
  ushort4 o;
  o.x = f2bf(v.x); o.y = f2bf(v.y); o.z = f2bf(v.z); o.w = f2bf(v.w);
  *(ushort4*)&dst[i] = o;
}

// ---------------------------------------------------------------- rope tables
__global__ __launch_bounds__(256) void build_rope_tables(float* __restrict__ ct,
                                                         float* __restrict__ st) {
  int i = blockIdx.x * 256 + threadIdx.x;     // < S_*32
  int pos = i >> 5, d2 = i & 31;
  float invf = powf(10000.0f, -(float)d2 / 32.0f);
  float fr = (float)pos * invf;
  ct[i] = cosf(fr);
  st[i] = sinf(fr);
}

// ---------------------------------------------------------------- GEMM  C = A * B^T
template <int OUT_BF16>
__global__ __launch_bounds__(256)
void gemm_bt(const ushort* __restrict__ A, const ushort* __restrict__ Bm,
             void* __restrict__ Cout, int Mdim, int Ndim, int Kdim) {
  __shared__ ushort As[128 * 32];
  __shared__ ushort Bs[128 * 32];
  int t = threadIdx.x;
  int w = t >> 6, l = t & 63;
  int m0 = blockIdx.y * 128, n0 = blockIdx.x * 128;
  int wr = (w >> 1) * 64, wc = (w & 1) * 64;
  int lrow = l & 15, lk8 = (l >> 4) * 8;
  int arow = t >> 2;
  int acol = (t & 3) * 8;

  f32x4 acc[4][4];
#pragma unroll
  for (int mi = 0; mi < 4; ++mi)
#pragma unroll
    for (int ni = 0; ni < 4; ++ni) acc[mi][ni] = f32x4{0.f, 0.f, 0.f, 0.f};

  for (int k0 = 0; k0 < Kdim; k0 += 32) {
    __syncthreads();
#pragma unroll
    for (int c = 0; c < 2; ++c) {
      gload_lds16(&A[(size_t)(m0 + arow + c * 64) * Kdim + k0 + acol],
                  &As[(c * 256 + w * 64) * 8]);
      gload_lds16(&Bm[(size_t)(n0 + arow + c * 64) * Kdim + k0 + acol],
                  &Bs[(c * 256 + w * 64) * 8]);
    }
    __syncthreads();
    short8 af[4], bfr[4];
#pragma unroll
    for (int i = 0; i < 4; ++i)
      af[i] = *(const short8*)&As[(wr + i * 16 + lrow) * 32 + lk8];
#pragma unroll
    for (int i = 0; i < 4; ++i)
      bfr[i] = *(const short8*)&Bs[(wc + i * 16 + lrow) * 32 + lk8];
#pragma unroll
    for (int mi = 0; mi < 4; ++mi)
#pragma unroll
      for (int ni = 0; ni < 4; ++ni)
        acc[mi][ni] = mfma_bf16(af[mi], bfr[ni], acc[mi][ni]);
  }

#pragma unroll
  for (int mi = 0; mi < 4; ++mi)
#pragma unroll
    for (int ni = 0; ni < 4; ++ni)
#pragma unroll
      for (int j = 0; j < 4; ++j) {
        int row = m0 + wr + mi * 16 + (l >> 4) * 4 + j;
        int col = n0 + wc + ni * 16 + lrow;
        float vv = acc[mi][ni][j];
        if (OUT_BF16)
          ((ushort*)Cout)[(size_t)row * Ndim + col] = f2bf(vv);
        else
          ((float*)Cout)[(size_t)row * Ndim + col] = vv;
      }
}

// ---------------------------------------------------------------- RoPE + scatter (q,k)
// q pre-scaled by 0.125*log2(e) so flash can use exp2.
__global__ __launch_bounds__(256)
void rope_scatter(const ushort* __restrict__ QKV, const float* __restrict__ ct,
                  const float* __restrict__ st, ushort* __restrict__ qb,
                  ushort* __restrict__ kb) {
  const float SC = 0.125f * 1.44269504f;
  int i = blockIdx.x * 256 + threadIdx.x;   // < M_*NH_*32
  int row = i >> 9;
  int rem = i & 511;
  int h = rem >> 5, d2 = rem & 31;
  int b = row >> 11, s = row & 2047;
  size_t base = (size_t)row * 3072;
  float c = ct[s * 32 + d2], sn = st[s * 32 + d2];
  size_t o = ((size_t)(b * NH_ + h) * S_ + s) * HD_;

  float x1 = bf2f(QKV[base + h * 64 + d2]);
  float x2 = bf2f(QKV[base + h * 64 + d2 + 32]);
  qb[o + d2]      = f2bf((x1 * c - x2 * sn) * SC);
  qb[o + d2 + 32] = f2bf((x2 * c + x1 * sn) * SC);

  x1 = bf2f(QKV[base + 1024 + h * 64 + d2]);
  x2 = bf2f(QKV[base + 1024 + h * 64 + d2 + 32]);
  kb[o + d2]      = f2bf(x1 * c - x2 * sn);
  kb[o + d2 + 32] = f2bf(x2 * c + x1 * sn);
}

// ---------------------------------------------------------------- V transpose
__global__ __launch_bounds__(256)
void transp_v(const ushort* __restrict__ QKV, ushort* __restrict__ vt) {
  __shared__ ushort T[64][72];
  int s0 = blockIdx.x * 64, bh = blockIdx.y;
  int b = bh >> 4, h = bh & 15;
  int t = threadIdx.x;
#pragma unroll
  for (int cc = 0; cc < 2; ++cc) {
    int slot = cc * 256 + t;
    int r = slot >> 3, c = slot & 7;
    short8 v = *(const short8*)
        &QKV[(size_t)(b * S_ + s0 + r) * 3072 + 2048 + h * 64 + c * 8];
#pragma unroll
    for (int i = 0; i < 8; ++i) T[c * 8 + i][r] = (ushort)v[i];
  }
  __syncthreads();
  ushort* dst = vt + (size_t)bh * HD_ * S_;
#pragma unroll
  for (int cc = 0; cc < 2; ++cc) {
    int slot = cc * 256 + t;
    int d = slot >> 3, c = slot & 7;
    *(short8*)&dst[(size_t)d * S_ + s0 + c * 8] = *(const short8*)&T[d][c * 8];
  }
}

// ---------------------------------------------------------------- flash attention v5
// QBLK=128, KVBLK=128, swapped-operand MFMA, lane-local softmax rows,
// shfl_xor reduces (known-good), cvt_pk packing, two-half PV via one P buffer.
__global__ __launch_bounds__(256, 2)
void flash_attn(const ushort* __restrict__ qb, const ushort* __restrict__ kb,
                const ushort* __restrict__ vt, ushort* __restrict__ ctx) {
  __shared__ ushort Ks[2][128 * 64];   // [key][d] swizzled
  __shared__ ushort Vs[2][64 * 128];   // [d][key] swizzled
  __shared__ ushort Ps[128 * 64];      // Q staging, then P (swizzled)
  int qt = (int)gridDim.x - 1 - (int)blockIdx.x;   // heavy blocks first
  int bh = blockIdx.y;
  int b = bh >> 4, h = bh & 15;
  int t = threadIdx.x, w = t >> 6, l = t & 63;
  int lrow = l & 15, g = l >> 4;
  int wrow = w * 32;
  const ushort* Q = qb + (size_t)bh * S_ * HD_;
  const ushort* K = kb + (size_t)bh * S_ * HD_;
  const ushort* V = vt + (size_t)bh * HD_ * S_;   // [64][2048]

  // prologue: Q (swizzled) into Ps; K/V tile 0
#pragma unroll
  for (int cc = 0; cc < 4; ++cc) {
    int slot = cc * 256 + t;
    int r = slot >> 3, c = slot & 7;
    int cs = (c ^ (r & 7)) << 3;
    gload_lds16(&Q[(size_t)(qt * 128 + r) * 64 + cs], &Ps[slot * 8]);
  }
#pragma unroll
  for (int cc = 0; cc < 4; ++cc) {
    int slot = cc * 256 + t;
    int r = slot >> 3, c = slot & 7;
    int cs = (c ^ (r & 7)) << 3;
    gload_lds16(&K[(size_t)r * 64 + cs], &Ks[0][slot * 8]);
  }
#pragma unroll
  for (int cc = 0; cc < 4; ++cc) {
    int slot = cc * 256 + t;
    int r = slot >> 4, c = slot & 15;
    int cs = (c ^ (r & 7)) << 3;
    gload_lds16(&V[(size_t)r * S_ + cs], &Vs[0][slot * 8]);
  }
  __syncthreads();

  short8 aq[2][2];
#pragma unroll
  for (int m = 0; m < 2; ++m)
#pragma unroll
    for (int ks = 0; ks < 2; ++ks)
      aq[m][ks] = *(const short8*)&Ps[swzK(wrow + m * 16 + lrow, ks * 4 + g)];
  __syncthreads();   // Ps now reusable for P

  float m_[2] = {-1e30f, -1e30f}, ls_[2] = {0.f, 0.f};
  f32x4 O[2][4];
#pragma unroll
  for (int m = 0; m < 2; ++m)
#pragma unroll
    for (int nf = 0; nf < 4; ++nf) O[m][nf] = f32x4{0.f, 0.f, 0.f, 0.f};

  int nkt = qt + 1;
  for (int kt = 0; kt < nkt; ++kt) {
    const ushort* Kc = Ks[kt & 1];
    const ushort* Vc = Vs[kt & 1];
    if (kt + 1 < nkt) {
      int nb = (kt + 1) & 1;
#pragma unroll
      for (int cc = 0; cc < 4; ++cc) {
        int slot = cc * 256 + t;
        int r = slot >> 3, c = slot & 7;
        int cs = (c ^ (r & 7)) << 3;
        gload_lds16(&K[(size_t)((kt + 1) * 128 + r) * 64 + cs], &Ks[nb][slot * 8]);
      }
#pragma unroll
      for (int cc = 0; cc < 4; ++cc) {
        int slot = cc * 256 + t;
        int r = slot >> 4, c = slot & 15;
        int cs = (c ^ (r & 7)) << 3;
        gload_lds16(&V[(size_t)r * S_ + (kt + 1) * 128 + cs], &Vs[nb][slot * 8]);
      }
    }

    // S^T = K Q^T : lane q = lrow; key = nf*16 + g*4 + j
    f32x4 sc[2][8];
#pragma unroll
    for (int m = 0; m < 2; ++m)
#pragma unroll
      for (int nf = 0; nf < 8; ++nf) sc[m][nf] = f32x4{0.f, 0.f, 0.f, 0.f};
    __builtin_amdgcn_s_setprio(1);
#pragma unroll
    for (int ks = 0; ks < 2; ++ks)
#pragma unroll
      for (int nf = 0; nf < 8; ++nf) {
        short8 bk = *(const short8*)&Kc[swzK(nf * 16 + lrow, ks * 4 + g)];
#pragma unroll
        for (int m = 0; m < 2; ++m)
          sc[m][nf] = mfma_bf16(bk, aq[m][ks], sc[m][nf]);
      }
    __builtin_amdgcn_s_setprio(0);

    int qbase = qt * 128 + wrow;
    if (kt * 128 + 127 > qbase) {   // wave-uniform
#pragma unroll
      for (int m = 0; m < 2; ++m) {
        int qi = qbase + m * 16 + lrow;
#pragma unroll
        for (int nf = 0; nf < 8; ++nf) {
          int kbase = kt * 128 + nf * 16 + g * 4;
#pragma unroll
          for (int j = 0; j < 4; ++j)
            if (kbase + j > qi) sc[m][nf][j] = -1e30f;
        }
      }
    }

    // row max per m: pairwise tree + 2 shuffles (known-good)
    float mx[2];
#pragma unroll
    for (int m = 0; m < 2; ++m) {
      f32x4 v4 = sc[m][0];
#pragma unroll
      for (int nf = 1; nf < 8; ++nf)
#pragma unroll
        for (int j = 0; j < 4; ++j) v4[j] = fmaxf(v4[j], sc[m][nf][j]);
      float a = fmaxf(fmaxf(v4[0], v4[1]), fmaxf(v4[2], v4[3]));
      a = fmaxf(a, __shfl_xor(a, 16));
      a = fmaxf(a, __shfl_xor(a, 32));
      mx[m] = a;
    }

    // defer-max (T13)
    bool nor = __all((mx[0] <= m_[0] + 8.f) && (mx[1] <= m_[1] + 8.f));
    if (!nor) {
#pragma unroll
      for (int m = 0; m < 2; ++m) {
        float mnew = fmaxf(m_[m], mx[m]);
        float al = exp2f(m_[m] - mnew);
        m_[m] = mnew;
        ls_[m] *= al;
#pragma unroll
        for (int nf = 0; nf < 4; ++nf)
#pragma unroll
          for (int j = 0; j < 4; ++j) O[m][nf][j] *= al;
      }
    }

    // exp2 + row sum
#pragma unroll
    for (int m = 0; m < 2; ++m) {
      f32x4 s4 = f32x4{0.f, 0.f, 0.f, 0.f};
#pragma unroll
      for (int nf = 0; nf < 8; ++nf)
#pragma unroll
        for (int j = 0; j < 4; ++j) {
          float p = exp2f(sc[m][nf][j] - m_[m]);
          sc[m][nf][j] = p;
          s4[j] += p;
        }
      float rs = (s4[0] + s4[1]) + (s4[2] + s4[3]);
      rs += __shfl_xor(rs, 16);
      rs += __shfl_xor(rs, 32);
      ls_[m] += rs;
    }

    // PV in two 64-key halves through the wave-private P buffer
#pragma unroll
    for (int half = 0; half < 2; ++half) {
#pragma unroll
      for (int m = 0; m < 2; ++m) {
        int prow = wrow + m * 16 + lrow;
#pragma unroll
        for (int nf2 = 0; nf2 < 4; ++nf2) {
          int nf = half * 4 + nf2;
          uint2 pk;
          pk.x = cvtpk(sc[m][nf][0], sc[m][nf][1]);
          pk.y = cvtpk(sc[m][nf][2], sc[m][nf][3]);
          // local key = nf2*16 + g*4 -> chunk nf2*2+(g>>1), +4 elems if g odd
          *(uint2*)&Ps[swzK(prow, nf2 * 2 + (g >> 1)) + (g & 1) * 4] = pk;
        }
      }
      __builtin_amdgcn_s_setprio(1);
#pragma unroll
      for (int ks2 = 0; ks2 < 2; ++ks2) {
        short8 ap[2];
#pragma unroll
        for (int m = 0; m < 2; ++m)
          ap[m] = *(const short8*)&Ps[swzK(wrow + m * 16 + lrow, ks2 * 4 + g)];
#pragma unroll
        for (int nf = 0; nf < 4; ++nf) {
          short8 bv = *(const short8*)&Vc[swzV(nf * 16 + lrow, half * 8 + ks2 * 4 + g)];
#pragma unroll
          for (int m = 0; m < 2; ++m) O[m][nf] = mfma_bf16(bv, ap[m], O[m][nf]);
        }
      }
      __builtin_amdgcn_s_setprio(0);
    }

    __syncthreads();   // next K/V tile staged; everyone done with current
  }

  // epilogue: lane q = lrow, d = nf*16 + g*4 + j
#pragma unroll
  for (int m = 0; m < 2; ++m) {
    float inv = 1.f / ls_[m];
    int srow = qt * 128 + wrow + m * 16 + lrow;
#pragma unroll
    for (int nf = 0; nf < 4; ++nf) {
      uint2 pk;
      pk.x = cvtpk(O[m][nf][0] * inv, O[m][nf][1] * inv);
      pk.y = cvtpk(O[m][nf][2] * inv, O[m][nf][3] * inv);
      *(uint2*)&ctx[((size_t)b * S_ + srow) * H_ + h * 64 + nf * 16 + g * 4] = pk;
    }
  }
}

// ---------------------------------------------------------------- launch
extern "C" void kernel_launch(void* const* d_in, const int* in_sizes, int n_in,
                              void* d_out, int out_size, void* d_ws, size_t ws_size,
                              hipStream_t stream) {
  const float* x  = (const float*)d_in[0];
  const float* Wq = (const float*)d_in[1];
  const float* Wk = (const float*)d_in[2];
  const float* Wv = (const float*)d_in[3];
  const float* Wo = (const float*)d_in[4];

  char* ws = (char*)d_ws;
  size_t off = 0;
  ushort* xb   = (ushort*)(ws + off); off += (size_t)M_ * H_ * 2;
  ushort* Wqkv = (ushort*)(ws + off); off += (size_t)3 * H_ * H_ * 2;
  ushort* Wob  = (ushort*)(ws + off); off += (size_t)H_ * H_ * 2;
  float*  ct   = (float*)(ws + off);  off += (size_t)S_ * 32 * 4;
  float*  st   = (float*)(ws + off);  off += (size_t)S_ * 32 * 4;
  ushort* QKV  = (ushort*)(ws + off); off += (size_t)M_ * 3 * H_ * 2;
  ushort* qb   = (ushort*)(ws + off); off += (size_t)M_ * H_ * 2;
  ushort* kb   = (ushort*)(ws + off); off += (size_t)M_ * H_ * 2;
  ushort* vtb  = (ushort*)(ws + off); off += (size_t)M_ * H_ * 2;
  ushort* ctx  = (ushort*)(ws + off); off += (size_t)M_ * H_ * 2;

  cvt_f2bf<<<M_ * H_ / 1024, 256, 0, stream>>>(x, xb, M_ * H_);
  cvt_w<<<dim3(H_ * H_ / 1024, 4), 256, 0, stream>>>(Wq, Wk, Wv, Wo, Wqkv, Wob);
  build_rope_tables<<<S_ * 32 / 256, 256, 0, stream>>>(ct, st);

  gemm_bt<1><<<dim3(3 * H_ / 128, M_ / 128), 256, 0, stream>>>(
      xb, Wqkv, QKV, M_, 3 * H_, H_);
  rope_scatter<<<M_ * NH_ * 32 / 256, 256, 0, stream>>>(QKV, ct, st, qb, kb);
  transp_v<<<dim3(S_ / 64, B_ * NH_), 256, 0, stream>>>(QKV, vtb);
  flash_attn<<<dim3(S_ / 128, B_ * NH_), 256, 0, stream>>>(qb, kb, vtb, ctx);
  gemm_bt<0><<<dim3(H_ / 128, M_ / 128), 256, 0, stream>>>(
      ctx, Wob, d_out, M_, H_, H_);
}

// Round 9
// 142.169 us; speedup vs baseline: 1.7232x; 1.1109x over previous
//
#include <hip/hip_runtime.h>

#define B_  2
#define S_  2048
#define H_  1024
#define NH_ 16
#define HD_ 64
#define M_  (B_ * S_)   // 4096

typedef short  short8  __attribute__((ext_vector_type(8)));
typedef __bf16 bf16x8  __attribute__((ext_vector_type(8)));
typedef float  f32x4   __attribute__((ext_vector_type(4)));

__device__ __forceinline__ ushort f2bf(float f) {
  union { float f; unsigned u; } v; v.f = f;
  unsigned r = v.u + 0x7fffu + ((v.u >> 16) & 1u);   // RNE
  return (ushort)(r >> 16);
}
__device__ __forceinline__ float bf2f(ushort u) {
  union { unsigned u; float f; } v; v.u = ((unsigned)u) << 16;
  return v.f;
}
// packed bf16 pair via HW cvt (RNE): dst.lo=bf16(lo), dst.hi=bf16(hi)
__device__ __forceinline__ unsigned cvtpk(float lo, float hi) {
  unsigned r;
  asm("v_cvt_pk_bf16_f32 %0, %1, %2" : "=v"(r) : "v"(lo), "v"(hi));
  return r;
}

__device__ __forceinline__ void gload_lds16(const void* g, void* l) {
  __builtin_amdgcn_global_load_lds(
      (const __attribute__((address_space(1))) void*)g,
      (__attribute__((address_space(3))) void*)l, 16, 0, 0);
}

__device__ __forceinline__ f32x4 mfma_bf16(short8 a, short8 b, f32x4 c) {
  return __builtin_amdgcn_mfma_f32_16x16x32_bf16(
      __builtin_bit_cast(bf16x8, a), __builtin_bit_cast(bf16x8, b), c, 0, 0, 0);
}

// swizzled element offsets; c = 16B chunk index
__device__ __forceinline__ int swzK(int r, int c) {   // [R][64] tiles
  return r * 64 + ((c ^ (r & 7)) << 3);
}
__device__ __forceinline__ int swzV(int r, int c) {   // [R][128] tiles
  return r * 128 + ((c ^ (r & 7)) << 3);
}

// reduce over lanes {l, l^16, l^32, l^48} — known-good shfl_xor pair.
// (permlane32_swap abandoned: both the builtin with aliased args AND the
//  "+v","+v" asm form let regalloc coalesce the two operands into one
//  register, collapsing the swap — 3 failed rounds, marginal upside.)
__device__ __forceinline__ float redmax64(float a) {
  a = fmaxf(a, __shfl_xor(a, 16));
  a = fmaxf(a, __shfl_xor(a, 32));
  return a;
}
__device__ __forceinline__ float redsum64(float a) {
  a += __shfl_xor(a, 16);
  a += __shfl_xor(a, 32);
  return a;
}

// ---------------------------------------------------------------- convert
__global__ __launch_bounds__(256) void cvt_f2bf(const float* __restrict__ src,
                                                ushort* __restrict__ dst, int n) {
  int i = (blockIdx.x * 256 + threadIdx.x) * 4;
  if (i < n) {
    float4 v = *(const float4*)&src[i];
    ushort4 o;
    o.x = f2bf(v.x); o.y = f2bf(v.y); o.z = f2bf(v.z); o.w = f2bf(v.w);
    *(ushort4*)&dst[i] = o;
  }
}

// all four weight matrices in one launch
__global__ __launch_bounds__(256)
void cvt_w(const float* __restrict__ Wq, const float* __restrict__ Wk,
           const float* __restrict__ Wv, const float* __restrict__ Wo,
           ushort* __restrict__ Wqkv, ushort* __restrict__ Wob) {
  int y = blockIdx.y;
  const float* src = (y == 0) ? Wq : (y == 1) ? Wk : (y == 2) ? Wv : Wo;
  ushort* dst = (y == 3) ? Wob : Wqkv + (size_t)y * H_ * H_;
  int i = (blockIdx.x * 256 + threadIdx.x) * 4;
  float4 v = *(const float4*)&src[i];
  ushort4 o;
  o.x = f2bf(v.x); o.y = f2bf(v.y); o.z = f2bf(v.z); o.w = f2bf(v.w);
  *(ushort4*)&dst[i] = o;
}

// ---------------------------------------------------------------- rope tables
__global__ __launch_bounds__(256) void build_rope_tables(float* __restrict__ ct,
                                                         float* __restrict__ st) {
  int i = blockIdx.x * 256 + threadIdx.x;     // < S_*32
  int pos = i >> 5, d2 = i & 31;
  float invf = powf(10000.0f, -(float)d2 / 32.0f);
  float fr = (float)pos * invf;
  ct[i] = cosf(fr);
  st[i] = sinf(fr);
}

// ---------------------------------------------------------------- GEMM  C = A * B^T
template <int OUT_BF16>
__global__ __launch_bounds__(256)
void gemm_bt(const ushort* __restrict__ A, const ushort* __restrict__ Bm,
             void* __restrict__ Cout, int Mdim, int Ndim, int Kdim) {
  __shared__ ushort As[128 * 32];
  __shared__ ushort Bs[128 * 32];
  int t = threadIdx.x;
  int w = t >> 6, l = t & 63;
  int m0 = blockIdx.y * 128, n0 = blockIdx.x * 128;
  int wr = (w >> 1) * 64, wc = (w & 1) * 64;
  int lrow = l & 15, lk8 = (l >> 4) * 8;
  int arow = t >> 2;
  int acol = (t & 3) * 8;

  f32x4 acc[4][4];
#pragma unroll
  for (int mi = 0; mi < 4; ++mi)
#pragma unroll
    for (int ni = 0; ni < 4; ++ni) acc[mi][ni] = f32x4{0.f, 0.f, 0.f, 0.f};

  for (int k0 = 0; k0 < Kdim; k0 += 32) {
    __syncthreads();
#pragma unroll
    for (int c = 0; c < 2; ++c) {
      gload_lds16(&A[(size_t)(m0 + arow + c * 64) * Kdim + k0 + acol],
                  &As[(c * 256 + w * 64) * 8]);
      gload_lds16(&Bm[(size_t)(n0 + arow + c * 64) * Kdim + k0 + acol],
                  &Bs[(c * 256 + w * 64) * 8]);
    }
    __syncthreads();
    short8 af[4], bfr[4];
#pragma unroll
    for (int i = 0; i < 4; ++i)
      af[i] = *(const short8*)&As[(wr + i * 16 + lrow) * 32 + lk8];
#pragma unroll
    for (int i = 0; i < 4; ++i)
      bfr[i] = *(const short8*)&Bs[(wc + i * 16 + lrow) * 32 + lk8];
#pragma unroll
    for (int mi = 0; mi < 4; ++mi)
#pragma unroll
      for (int ni = 0; ni < 4; ++ni)
        acc[mi][ni] = mfma_bf16(af[mi], bfr[ni], acc[mi][ni]);
  }

#pragma unroll
  for (int mi = 0; mi < 4; ++mi)
#pragma unroll
    for (int ni = 0; ni < 4; ++ni)
#pragma unroll
      for (int j = 0; j < 4; ++j) {
        int row = m0 + wr + mi * 16 + (l >> 4) * 4 + j;
        int col = n0 + wc + ni * 16 + lrow;
        float vv = acc[mi][ni][j];
        if (OUT_BF16)
          ((ushort*)Cout)[(size_t)row * Ndim + col] = f2bf(vv);
        else
          ((float*)Cout)[(size_t)row * Ndim + col] = vv;
      }
}

// ---------------------------------------------------------------- RoPE + scatter (q,k)
// q pre-scaled by 0.125*log2(e) so flash can use exp2.
__global__ __launch_bounds__(256)
void rope_scatter(const ushort* __restrict__ QKV, const float* __restrict__ ct,
                  const float* __restrict__ st, ushort* __restrict__ qb,
                  ushort* __restrict__ kb) {
  const float SC = 0.125f * 1.44269504f;
  int i = blockIdx.x * 256 + threadIdx.x;   // < M_*NH_*32
  int row = i >> 9;
  int rem = i & 511;
  int h = rem >> 5, d2 = rem & 31;
  int b = row >> 11, s = row & 2047;
  size_t base = (size_t)row * 3072;
  float c = ct[s * 32 + d2], sn = st[s * 32 + d2];
  size_t o = ((size_t)(b * NH_ + h) * S_ + s) * HD_;

  float x1 = bf2f(QKV[base + h * 64 + d2]);
  float x2 = bf2f(QKV[base + h * 64 + d2 + 32]);
  qb[o + d2]      = f2bf((x1 * c - x2 * sn) * SC);
  qb[o + d2 + 32] = f2bf((x2 * c + x1 * sn) * SC);

  x1 = bf2f(QKV[base + 1024 + h * 64 + d2]);
  x2 = bf2f(QKV[base + 1024 + h * 64 + d2 + 32]);
  kb[o + d2]      = f2bf(x1 * c - x2 * sn);
  kb[o + d2 + 32] = f2bf(x2 * c + x1 * sn);
}

// ---------------------------------------------------------------- V transpose
__global__ __launch_bounds__(256)
void transp_v(const ushort* __restrict__ QKV, ushort* __restrict__ vt) {
  __shared__ ushort T[64][72];
  int s0 = blockIdx.x * 64, bh = blockIdx.y;
  int b = bh >> 4, h = bh & 15;
  int t = threadIdx.x;
#pragma unroll
  for (int cc = 0; cc < 2; ++cc) {
    int slot = cc * 256 + t;
    int r = slot >> 3, c = slot & 7;
    short8 v = *(const short8*)
        &QKV[(size_t)(b * S_ + s0 + r) * 3072 + 2048 + h * 64 + c * 8];
#pragma unroll
    for (int i = 0; i < 8; ++i) T[c * 8 + i][r] = (ushort)v[i];
  }
  __syncthreads();
  ushort* dst = vt + (size_t)bh * HD_ * S_;
#pragma unroll
  for (int cc = 0; cc < 2; ++cc) {
    int slot = cc * 256 + t;
    int d = slot >> 3, c = slot & 7;
    *(short8*)&dst[(size_t)d * S_ + s0 + c * 8] = *(const short8*)&T[d][c * 8];
  }
}

// ---------------------------------------------------------------- flash attention v7
// R7 structure (KVBLK=128, shfl_xor reduces) + CU-pairing load balance:
// co-resident blocks (x,y) and (x,y+16) get qt = 15-x and x -> 17 iters/CU.
__global__ __launch_bounds__(256, 2)
void flash_attn(const ushort* __restrict__ qb, const ushort* __restrict__ kb,
                const ushort* __restrict__ vt, ushort* __restrict__ ctx) {
  __shared__ ushort Ks[2][128 * 64];   // [key][d] swizzled
  __shared__ ushort Vs[2][64 * 128];   // [d][key] swizzled
  __shared__ ushort Ps[128 * 64];      // Q staging, then P (swizzled)
  int bh = blockIdx.y;
  int qt = (blockIdx.y & 16) ? (int)blockIdx.x : (15 - (int)blockIdx.x);
  int b = bh >> 4, h = bh & 15;
  int t = threadIdx.x, w = t >> 6, l = t & 63;
  int lrow = l & 15, g = l >> 4;
  int wrow = w * 32;
  const ushort* Q = qb + (size_t)bh * S_ * HD_;
  const ushort* K = kb + (size_t)bh * S_ * HD_;
  const ushort* V = vt + (size_t)bh * HD_ * S_;   // [64][2048]

  // prologue: Q (swizzled) into Ps; K/V tile 0
#pragma unroll
  for (int cc = 0; cc < 4; ++cc) {
    int slot = cc * 256 + t;
    int r = slot >> 3, c = slot & 7;
    int cs = (c ^ (r & 7)) << 3;
    gload_lds16(&Q[(size_t)(qt * 128 + r) * 64 + cs], &Ps[slot * 8]);
  }
#pragma unroll
  for (int cc = 0; cc < 4; ++cc) {
    int slot = cc * 256 + t;
    int r = slot >> 3, c = slot & 7;
    int cs = (c ^ (r & 7)) << 3;
    gload_lds16(&K[(size_t)r * 64 + cs], &Ks[0][slot * 8]);
  }
#pragma unroll
  for (int cc = 0; cc < 4; ++cc) {
    int slot = cc * 256 + t;
    int r = slot >> 4, c = slot & 15;
    int cs = (c ^ (r & 7)) << 3;
    gload_lds16(&V[(size_t)r * S_ + cs], &Vs[0][slot * 8]);
  }
  __syncthreads();

  short8 aq[2][2];
#pragma unroll
  for (int m = 0; m < 2; ++m)
#pragma unroll
    for (int ks = 0; ks < 2; ++ks)
      aq[m][ks] = *(const short8*)&Ps[swzK(wrow + m * 16 + lrow, ks * 4 + g)];
  __syncthreads();   // Ps now reusable for P

  float m_[2] = {-1e30f, -1e30f}, ls_[2] = {0.f, 0.f};
  f32x4 O[2][4];
#pragma unroll
  for (int m = 0; m < 2; ++m)
#pragma unroll
    for (int nf = 0; nf < 4; ++nf) O[m][nf] = f32x4{0.f, 0.f, 0.f, 0.f};

  int nkt = qt + 1;
  for (int kt = 0; kt < nkt; ++kt) {
    const ushort* Kc = Ks[kt & 1];
    const ushort* Vc = Vs[kt & 1];
    if (kt + 1 < nkt) {
      int nb = (kt + 1) & 1;
#pragma unroll
      for (int cc = 0; cc < 4; ++cc) {
        int slot = cc * 256 + t;
        int r = slot >> 3, c = slot & 7;
        int cs = (c ^ (r & 7)) << 3;
        gload_lds16(&K[(size_t)((kt + 1) * 128 + r) * 64 + cs], &Ks[nb][slot * 8]);
      }
#pragma unroll
      for (int cc = 0; cc < 4; ++cc) {
        int slot = cc * 256 + t;
        int r = slot >> 4, c = slot & 15;
        int cs = (c ^ (r & 7)) << 3;
        gload_lds16(&V[(size_t)r * S_ + (kt + 1) * 128 + cs], &Vs[nb][slot * 8]);
      }
    }

    // S^T = K Q^T : lane q = lrow; key = nf*16 + g*4 + j
    f32x4 sc[2][8];
#pragma unroll
    for (int m = 0; m < 2; ++m)
#pragma unroll
      for (int nf = 0; nf < 8; ++nf) sc[m][nf] = f32x4{0.f, 0.f, 0.f, 0.f};
    __builtin_amdgcn_s_setprio(1);
#pragma unroll
    for (int ks = 0; ks < 2; ++ks)
#pragma unroll
      for (int nf = 0; nf < 8; ++nf) {
        short8 bk = *(const short8*)&Kc[swzK(nf * 16 + lrow, ks * 4 + g)];
#pragma unroll
        for (int m = 0; m < 2; ++m)
          sc[m][nf] = mfma_bf16(bk, aq[m][ks], sc[m][nf]);
      }
    __builtin_amdgcn_s_setprio(0);

    int qbase = qt * 128 + wrow;
    if (kt * 128 + 127 > qbase) {   // wave-uniform
#pragma unroll
      for (int m = 0; m < 2; ++m) {
        int qi = qbase + m * 16 + lrow;
#pragma unroll
        for (int nf = 0; nf < 8; ++nf) {
          int kbase = kt * 128 + nf * 16 + g * 4;
#pragma unroll
          for (int j = 0; j < 4; ++j)
            if (kbase + j > qi) sc[m][nf][j] = -1e30f;
        }
      }
    }

    // row max per m: pairwise tree + 2 shuffles
    float mx[2];
#pragma unroll
    for (int m = 0; m < 2; ++m) {
      f32x4 v4 = sc[m][0];
#pragma unroll
      for (int nf = 1; nf < 8; ++nf)
#pragma unroll
        for (int j = 0; j < 4; ++j) v4[j] = fmaxf(v4[j], sc[m][nf][j]);
      float a = fmaxf(fmaxf(v4[0], v4[1]), fmaxf(v4[2], v4[3]));
      mx[m] = redmax64(a);
    }

    // defer-max (T13)
    bool nor = __all((mx[0] <= m_[0] + 8.f) && (mx[1] <= m_[1] + 8.f));
    if (!nor) {
#pragma unroll
      for (int m = 0; m < 2; ++m) {
        float mnew = fmaxf(m_[m], mx[m]);
        float al = exp2f(m_[m] - mnew);
        m_[m] = mnew;
        ls_[m] *= al;
#pragma unroll
        for (int nf = 0; nf < 4; ++nf)
#pragma unroll
          for (int j = 0; j < 4; ++j) O[m][nf][j] *= al;
      }
    }

    // exp2 + row sum
#pragma unroll
    for (int m = 0; m < 2; ++m) {
      f32x4 s4 = f32x4{0.f, 0.f, 0.f, 0.f};
#pragma unroll
      for (int nf = 0; nf < 8; ++nf)
#pragma unroll
        for (int j = 0; j < 4; ++j) {
          float p = exp2f(sc[m][nf][j] - m_[m]);
          sc[m][nf][j] = p;
          s4[j] += p;
        }
      float rs = (s4[0] + s4[1]) + (s4[2] + s4[3]);
      ls_[m] += redsum64(rs);
    }

    // PV in two 64-key halves through the wave-private P buffer
#pragma unroll
    for (int half = 0; half < 2; ++half) {
#pragma unroll
      for (int m = 0; m < 2; ++m) {
        int prow = wrow + m * 16 + lrow;
#pragma unroll
        for (int nf2 = 0; nf2 < 4; ++nf2) {
          int nf = half * 4 + nf2;
          uint2 pk;
          pk.x = cvtpk(sc[m][nf][0], sc[m][nf][1]);
          pk.y = cvtpk(sc[m][nf][2], sc[m][nf][3]);
          // local key = nf2*16 + g*4 -> chunk nf2*2+(g>>1), +4 elems if g odd
          *(uint2*)&Ps[swzK(prow, nf2 * 2 + (g >> 1)) + (g & 1) * 4] = pk;
        }
      }
      __builtin_amdgcn_s_setprio(1);
#pragma unroll
      for (int ks2 = 0; ks2 < 2; ++ks2) {
        short8 ap[2];
#pragma unroll
        for (int m = 0; m < 2; ++m)
          ap[m] = *(const short8*)&Ps[swzK(wrow + m * 16 + lrow, ks2 * 4 + g)];
#pragma unroll
        for (int nf = 0; nf < 4; ++nf) {
          short8 bv = *(const short8*)&Vc[swzV(nf * 16 + lrow, half * 8 + ks2 * 4 + g)];
#pragma unroll
          for (int m = 0; m < 2; ++m) O[m][nf] = mfma_bf16(bv, ap[m], O[m][nf]);
        }
      }
      __builtin_amdgcn_s_setprio(0);
    }

    __syncthreads();   // next K/V tile staged; everyone done with current
  }

  // epilogue: lane q = lrow, d = nf*16 + g*4 + j
#pragma unroll
  for (int m = 0; m < 2; ++m) {
    float inv = 1.f / ls_[m];
    int srow = qt * 128 + wrow + m * 16 + lrow;
#pragma unroll
    for (int nf = 0; nf < 4; ++nf) {
      uint2 pk;
      pk.x = cvtpk(O[m][nf][0] * inv, O[m][nf][1] * inv);
      pk.y = cvtpk(O[m][nf][2] * inv, O[m][nf][3] * inv);
      *(uint2*)&ctx[((size_t)b * S_ + srow) * H_ + h * 64 + nf * 16 + g * 4] = pk;
    }
  }
}

// ---------------------------------------------------------------- launch
extern "C" void kernel_launch(void* const* d_in, const int* in_sizes, int n_in,
                              void* d_out, int out_size, void* d_ws, size_t ws_size,
                              hipStream_t stream) {
  const float* x  = (const float*)d_in[0];
  const float* Wq = (const float*)d_in[1];
  const float* Wk = (const float*)d_in[2];
  const float* Wv = (const float*)d_in[3];
  const float* Wo = (const float*)d_in[4];

  char* ws = (char*)d_ws;
  size_t off = 0;
  ushort* xb   = (ushort*)(ws + off); off += (size_t)M_ * H_ * 2;
  ushort* Wqkv = (ushort*)(ws + off); off += (size_t)3 * H_ * H_ * 2;
  ushort* Wob  = (ushort*)(ws + off); off += (size_t)H_ * H_ * 2;
  float*  ct   = (float*)(ws + off);  off += (size_t)S_ * 32 * 4;
  float*  st   = (float*)(ws + off);  off += (size_t)S_ * 32 * 4;
  ushort* QKV  = (ushort*)(ws + off); off += (size_t)M_ * 3 * H_ * 2;
  ushort* qb   = (ushort*)(ws + off); off += (size_t)M_ * H_ * 2;
  ushort* kb   = (ushort*)(ws + off); off += (size_t)M_ * H_ * 2;
  ushort* vtb  = (ushort*)(ws + off); off += (size_t)M_ * H_ * 2;
  ushort* ctx  = (ushort*)(ws + off); off += (size_t)M_ * H_ * 2;

  cvt_f2bf<<<M_ * H_ / 1024, 256, 0, stream>>>(x, xb, M_ * H_);
  cvt_w<<<dim3(H_ * H_ / 1024, 4), 256, 0, stream>>>(Wq, Wk, Wv, Wo, Wqkv, Wob);
  build_rope_tables<<<S_ * 32 / 256, 256, 0, stream>>>(ct, st);

  gemm_bt<1><<<dim3(3 * H_ / 128, M_ / 128), 256, 0, stream>>>(
      xb, Wqkv, QKV, M_, 3 * H_, H_);
  rope_scatter<<<M_ * NH_ * 32 / 256, 256, 0, stream>>>(QKV, ct, st, qb, kb);
  transp_v<<<dim3(S_ / 64, B_ * NH_), 256, 0, stream>>>(QKV, vtb);
  flash_attn<<<dim3(S_ / 128, B_ * NH_), 256, 0, stream>>>(qb, kb, vtb, ctx);
  gemm_bt<0><<<dim3(H_ / 128, M_ / 128), 256, 0, stream>>>(
      ctx, Wob, d_out, M_, H_, H_);
}

// Round 10
// 136.474 us; speedup vs baseline: 1.7951x; 1.0417x over previous
//
#include <hip/hip_runtime.h>

#define B_  2
#define S_  2048
#define H_  1024
#define NH_ 16
#define HD_ 64
#define M_  (B_ * S_)   // 4096

typedef short  short8  __attribute__((ext_vector_type(8)));
typedef __bf16 bf16x8  __attribute__((ext_vector_type(8)));
typedef float  f32x4   __attribute__((ext_vector_type(4)));

__device__ __forceinline__ ushort f2bf(float f) {
  union { float f; unsigned u; } v; v.f = f;
  unsigned r = v.u + 0x7fffu + ((v.u >> 16) & 1u);   // RNE
  return (ushort)(r >> 16);
}
__device__ __forceinline__ float bf2f(ushort u) {
  union { unsigned u; float f; } v; v.u = ((unsigned)u) << 16;
  return v.f;
}
// packed bf16 pair via HW cvt (RNE): dst.lo=bf16(lo), dst.hi=bf16(hi)
__device__ __forceinline__ unsigned cvtpk(float lo, float hi) {
  unsigned r;
  asm("v_cvt_pk_bf16_f32 %0, %1, %2" : "=v"(r) : "v"(lo), "v"(hi));
  return r;
}

__device__ __forceinline__ void gload_lds16(const void* g, void* l) {
  __builtin_amdgcn_global_load_lds(
      (const __attribute__((address_space(1))) void*)g,
      (__attribute__((address_space(3))) void*)l, 16, 0, 0);
}

__device__ __forceinline__ f32x4 mfma_bf16(short8 a, short8 b, f32x4 c) {
  return __builtin_amdgcn_mfma_f32_16x16x32_bf16(
      __builtin_bit_cast(bf16x8, a), __builtin_bit_cast(bf16x8, b), c, 0, 0, 0);
}

// swizzled element offsets; c = 16B chunk index
__device__ __forceinline__ int swzK(int r, int c) {   // [R][64] tiles
  return r * 64 + ((c ^ (r & 7)) << 3);
}
__device__ __forceinline__ int swzV(int r, int c) {   // [R][128] tiles
  return r * 128 + ((c ^ (r & 7)) << 3);
}

// reduce over lanes {l, l^16, l^32, l^48} — known-good shfl_xor pair
__device__ __forceinline__ float redmax64(float a) {
  a = fmaxf(a, __shfl_xor(a, 16));
  a = fmaxf(a, __shfl_xor(a, 32));
  return a;
}
__device__ __forceinline__ float redsum64(float a) {
  a += __shfl_xor(a, 16);
  a += __shfl_xor(a, 32);
  return a;
}

// ---------------------------------------------------------------- convert
__global__ __launch_bounds__(256) void cvt_f2bf(const float* __restrict__ src,
                                                ushort* __restrict__ dst, int n) {
  int i = (blockIdx.x * 256 + threadIdx.x) * 4;
  if (i < n) {
    float4 v = *(const float4*)&src[i];
    ushort4 o;
    o.x = f2bf(v.x); o.y = f2bf(v.y); o.z = f2bf(v.z); o.w = f2bf(v.w);
    *(ushort4*)&dst[i] = o;
  }
}

// all four weight matrices in one launch
__global__ __launch_bounds__(256)
void cvt_w(const float* __restrict__ Wq, const float* __restrict__ Wk,
           const float* __restrict__ Wv, const float* __restrict__ Wo,
           ushort* __restrict__ Wqkv, ushort* __restrict__ Wob) {
  int y = blockIdx.y;
  const float* src = (y == 0) ? Wq : (y == 1) ? Wk : (y == 2) ? Wv : Wo;
  ushort* dst = (y == 3) ? Wob : Wqkv + (size_t)y * H_ * H_;
  int i = (blockIdx.x * 256 + threadIdx.x) * 4;
  float4 v = *(const float4*)&src[i];
  ushort4 o;
  o.x = f2bf(v.x); o.y = f2bf(v.y); o.z = f2bf(v.z); o.w = f2bf(v.w);
  *(ushort4*)&dst[i] = o;
}

// ---------------------------------------------------------------- rope tables
__global__ __launch_bounds__(256) void build_rope_tables(float* __restrict__ ct,
                                                         float* __restrict__ st) {
  int i = blockIdx.x * 256 + threadIdx.x;     // < S_*32
  int pos = i >> 5, d2 = i & 31;
  float invf = powf(10000.0f, -(float)d2 / 32.0f);
  float fr = (float)pos * invf;
  ct[i] = cosf(fr);
  st[i] = sinf(fr);
}

// ---------------------------------------------------------------- GEMM  C = A * B^T
template <int OUT_BF16>
__global__ __launch_bounds__(256)
void gemm_bt(const ushort* __restrict__ A, const ushort* __restrict__ Bm,
             void* __restrict__ Cout, int Mdim, int Ndim, int Kdim) {
  __shared__ ushort As[128 * 32];
  __shared__ ushort Bs[128 * 32];
  int t = threadIdx.x;
  int w = t >> 6, l = t & 63;
  int m0 = blockIdx.y * 128, n0 = blockIdx.x * 128;
  int wr = (w >> 1) * 64, wc = (w & 1) * 64;
  int lrow = l & 15, lk8 = (l >> 4) * 8;
  int arow = t >> 2;
  int acol = (t & 3) * 8;

  f32x4 acc[4][4];
#pragma unroll
  for (int mi = 0; mi < 4; ++mi)
#pragma unroll
    for (int ni = 0; ni < 4; ++ni) acc[mi][ni] = f32x4{0.f, 0.f, 0.f, 0.f};

  for (int k0 = 0; k0 < Kdim; k0 += 32) {
    __syncthreads();
#pragma unroll
    for (int c = 0; c < 2; ++c) {
      gload_lds16(&A[(size_t)(m0 + arow + c * 64) * Kdim + k0 + acol],
                  &As[(c * 256 + w * 64) * 8]);
      gload_lds16(&Bm[(size_t)(n0 + arow + c * 64) * Kdim + k0 + acol],
                  &Bs[(c * 256 + w * 64) * 8]);
    }
    __syncthreads();
    short8 af[4], bfr[4];
#pragma unroll
    for (int i = 0; i < 4; ++i)
      af[i] = *(const short8*)&As[(wr + i * 16 + lrow) * 32 + lk8];
#pragma unroll
    for (int i = 0; i < 4; ++i)
      bfr[i] = *(const short8*)&Bs[(wc + i * 16 + lrow) * 32 + lk8];
#pragma unroll
    for (int mi = 0; mi < 4; ++mi)
#pragma unroll
      for (int ni = 0; ni < 4; ++ni)
        acc[mi][ni] = mfma_bf16(af[mi], bfr[ni], acc[mi][ni]);
  }

#pragma unroll
  for (int mi = 0; mi < 4; ++mi)
#pragma unroll
    for (int ni = 0; ni < 4; ++ni)
#pragma unroll
      for (int j = 0; j < 4; ++j) {
        int row = m0 + wr + mi * 16 + (l >> 4) * 4 + j;
        int col = n0 + wc + ni * 16 + lrow;
        float vv = acc[mi][ni][j];
        if (OUT_BF16)
          ((ushort*)Cout)[(size_t)row * Ndim + col] = f2bf(vv);
        else
          ((float*)Cout)[(size_t)row * Ndim + col] = vv;
      }
}

// ---------------------------------------------------------------- RoPE + scatter (q,k)
// q pre-scaled by 0.125*log2(e) so flash can use exp2.
__global__ __launch_bounds__(256)
void rope_scatter(const ushort* __restrict__ QKV, const float* __restrict__ ct,
                  const float* __restrict__ st, ushort* __restrict__ qb,
                  ushort* __restrict__ kb) {
  const float SC = 0.125f * 1.44269504f;
  int i = blockIdx.x * 256 + threadIdx.x;   // < M_*NH_*32
  int row = i >> 9;
  int rem = i & 511;
  int h = rem >> 5, d2 = rem & 31;
  int b = row >> 11, s = row & 2047;
  size_t base = (size_t)row * 3072;
  float c = ct[s * 32 + d2], sn = st[s * 32 + d2];
  size_t o = ((size_t)(b * NH_ + h) * S_ + s) * HD_;

  float x1 = bf2f(QKV[base + h * 64 + d2]);
  float x2 = bf2f(QKV[base + h * 64 + d2 + 32]);
  qb[o + d2]      = f2bf((x1 * c - x2 * sn) * SC);
  qb[o + d2 + 32] = f2bf((x2 * c + x1 * sn) * SC);

  x1 = bf2f(QKV[base + 1024 + h * 64 + d2]);
  x2 = bf2f(QKV[base + 1024 + h * 64 + d2 + 32]);
  kb[o + d2]      = f2bf(x1 * c - x2 * sn);
  kb[o + d2 + 32] = f2bf(x2 * c + x1 * sn);
}

// ---------------------------------------------------------------- V transpose
__global__ __launch_bounds__(256)
void transp_v(const ushort* __restrict__ QKV, ushort* __restrict__ vt) {
  __shared__ ushort T[64][72];
  int s0 = blockIdx.x * 64, bh = blockIdx.y;
  int b = bh >> 4, h = bh & 15;
  int t = threadIdx.x;
#pragma unroll
  for (int cc = 0; cc < 2; ++cc) {
    int slot = cc * 256 + t;
    int r = slot >> 3, c = slot & 7;
    short8 v = *(const short8*)
        &QKV[(size_t)(b * S_ + s0 + r) * 3072 + 2048 + h * 64 + c * 8];
#pragma unroll
    for (int i = 0; i < 8; ++i) T[c * 8 + i][r] = (ushort)v[i];
  }
  __syncthreads();
  ushort* dst = vt + (size_t)bh * HD_ * S_;
#pragma unroll
  for (int cc = 0; cc < 2; ++cc) {
    int slot = cc * 256 + t;
    int d = slot >> 3, c = slot & 7;
    *(short8*)&dst[(size_t)d * S_ + s0 + c * 8] = *(const short8*)&T[d][c * 8];
  }
}

// ---------------------------------------------------------------- flash attention v8
// 512 threads / 8 waves, each wave 16 q-rows. Same tiles + barriers as v7;
// 16 waves/CU (4/SIMD) doubles latency hiding of the softmax chain.
__global__ __launch_bounds__(512, 4)
void flash_attn(const ushort* __restrict__ qb, const ushort* __restrict__ kb,
                const ushort* __restrict__ vt, ushort* __restrict__ ctx) {
  __shared__ ushort Ks[2][128 * 64];   // [key][d] swizzled
  __shared__ ushort Vs[2][64 * 128];   // [d][key] swizzled
  __shared__ ushort Ps[128 * 64];      // Q staging, then P (swizzled)
  int bh = blockIdx.y;
  int qt = (blockIdx.y & 16) ? (int)blockIdx.x : (15 - (int)blockIdx.x);
  int b = bh >> 4, h = bh & 15;
  int t = threadIdx.x, w = t >> 6, l = t & 63;
  int lrow = l & 15, g = l >> 4;
  int wrow = w * 16;
  const ushort* Q = qb + (size_t)bh * S_ * HD_;
  const ushort* K = kb + (size_t)bh * S_ * HD_;
  const ushort* V = vt + (size_t)bh * HD_ * S_;   // [64][2048]

  // prologue: Q (swizzled) into Ps; K/V tile 0   (512 thr -> 2 passes each)
#pragma unroll
  for (int cc = 0; cc < 2; ++cc) {
    int slot = cc * 512 + t;
    int r = slot >> 3, c = slot & 7;
    int cs = (c ^ (r & 7)) << 3;
    gload_lds16(&Q[(size_t)(qt * 128 + r) * 64 + cs], &Ps[slot * 8]);
  }
#pragma unroll
  for (int cc = 0; cc < 2; ++cc) {
    int slot = cc * 512 + t;
    int r = slot >> 3, c = slot & 7;
    int cs = (c ^ (r & 7)) << 3;
    gload_lds16(&K[(size_t)r * 64 + cs], &Ks[0][slot * 8]);
  }
#pragma unroll
  for (int cc = 0; cc < 2; ++cc) {
    int slot = cc * 512 + t;
    int r = slot >> 4, c = slot & 15;
    int cs = (c ^ (r & 7)) << 3;
    gload_lds16(&V[(size_t)r * S_ + cs], &Vs[0][slot * 8]);
  }
  __syncthreads();

  short8 aq[2];
#pragma unroll
  for (int ks = 0; ks < 2; ++ks)
    aq[ks] = *(const short8*)&Ps[swzK(wrow + lrow, ks * 4 + g)];
  __syncthreads();   // Ps now reusable for P

  float m_ = -1e30f, ls_ = 0.f;
  f32x4 O[4];
#pragma unroll
  for (int nf = 0; nf < 4; ++nf) O[nf] = f32x4{0.f, 0.f, 0.f, 0.f};

  int nkt = qt + 1;
  for (int kt = 0; kt < nkt; ++kt) {
    const ushort* Kc = Ks[kt & 1];
    const ushort* Vc = Vs[kt & 1];
    if (kt + 1 < nkt) {
      int nb = (kt + 1) & 1;
#pragma unroll
      for (int cc = 0; cc < 2; ++cc) {
        int slot = cc * 512 + t;
        int r = slot >> 3, c = slot & 7;
        int cs = (c ^ (r & 7)) << 3;
        gload_lds16(&K[(size_t)((kt + 1) * 128 + r) * 64 + cs], &Ks[nb][slot * 8]);
      }
#pragma unroll
      for (int cc = 0; cc < 2; ++cc) {
        int slot = cc * 512 + t;
        int r = slot >> 4, c = slot & 15;
        int cs = (c ^ (r & 7)) << 3;
        gload_lds16(&V[(size_t)r * S_ + (kt + 1) * 128 + cs], &Vs[nb][slot * 8]);
      }
    }

    // S^T = K Q^T : lane q = wrow+lrow; key = nf*16 + g*4 + j
    f32x4 sc[8];
#pragma unroll
    for (int nf = 0; nf < 8; ++nf) sc[nf] = f32x4{0.f, 0.f, 0.f, 0.f};
    __builtin_amdgcn_s_setprio(1);
#pragma unroll
    for (int ks = 0; ks < 2; ++ks)
#pragma unroll
      for (int nf = 0; nf < 8; ++nf) {
        short8 bk = *(const short8*)&Kc[swzK(nf * 16 + lrow, ks * 4 + g)];
        sc[nf] = mfma_bf16(bk, aq[ks], sc[nf]);
      }
    __builtin_amdgcn_s_setprio(0);

    int qbase = qt * 128 + wrow;
    if (kt * 128 + 127 > qbase) {   // wave-uniform
      int qi = qbase + lrow;
#pragma unroll
      for (int nf = 0; nf < 8; ++nf) {
        int kbase = kt * 128 + nf * 16 + g * 4;
#pragma unroll
        for (int j = 0; j < 4; ++j)
          if (kbase + j > qi) sc[nf][j] = -1e30f;
      }
    }

    // row max: pairwise tree + 2 shuffles
    f32x4 v4 = sc[0];
#pragma unroll
    for (int nf = 1; nf < 8; ++nf)
#pragma unroll
      for (int j = 0; j < 4; ++j) v4[j] = fmaxf(v4[j], sc[nf][j]);
    float mx = redmax64(fmaxf(fmaxf(v4[0], v4[1]), fmaxf(v4[2], v4[3])));

    // defer-max (T13)
    bool nor = __all(mx <= m_ + 8.f);
    if (!nor) {
      float mnew = fmaxf(m_, mx);
      float al = exp2f(m_ - mnew);
      m_ = mnew;
      ls_ *= al;
#pragma unroll
      for (int nf = 0; nf < 4; ++nf)
#pragma unroll
        for (int j = 0; j < 4; ++j) O[nf][j] *= al;
    }

    // exp2 + row sum
    f32x4 s4 = f32x4{0.f, 0.f, 0.f, 0.f};
#pragma unroll
    for (int nf = 0; nf < 8; ++nf)
#pragma unroll
      for (int j = 0; j < 4; ++j) {
        float p = exp2f(sc[nf][j] - m_);
        sc[nf][j] = p;
        s4[j] += p;
      }
    ls_ += redsum64((s4[0] + s4[1]) + (s4[2] + s4[3]));

    // PV in two 64-key halves through the wave-private P rows
#pragma unroll
    for (int half = 0; half < 2; ++half) {
      int prow = wrow + lrow;
#pragma unroll
      for (int nf2 = 0; nf2 < 4; ++nf2) {
        int nf = half * 4 + nf2;
        uint2 pk;
        pk.x = cvtpk(sc[nf][0], sc[nf][1]);
        pk.y = cvtpk(sc[nf][2], sc[nf][3]);
        // local key = nf2*16 + g*4 -> chunk nf2*2+(g>>1), +4 elems if g odd
        *(uint2*)&Ps[swzK(prow, nf2 * 2 + (g >> 1)) + (g & 1) * 4] = pk;
      }
      __builtin_amdgcn_s_setprio(1);
#pragma unroll
      for (int ks2 = 0; ks2 < 2; ++ks2) {
        short8 ap = *(const short8*)&Ps[swzK(wrow + lrow, ks2 * 4 + g)];
#pragma unroll
        for (int nf = 0; nf < 4; ++nf) {
          short8 bv = *(const short8*)&Vc[swzV(nf * 16 + lrow, half * 8 + ks2 * 4 + g)];
          O[nf] = mfma_bf16(bv, ap, O[nf]);
        }
      }
      __builtin_amdgcn_s_setprio(0);
    }

    __syncthreads();   // next K/V tile staged; everyone done with current
  }

  // epilogue: lane q = wrow+lrow, d = nf*16 + g*4 + j
  float inv = 1.f / ls_;
  int srow = qt * 128 + wrow + lrow;
#pragma unroll
  for (int nf = 0; nf < 4; ++nf) {
    uint2 pk;
    pk.x = cvtpk(O[nf][0] * inv, O[nf][1] * inv);
    pk.y = cvtpk(O[nf][2] * inv, O[nf][3] * inv);
    *(uint2*)&ctx[((size_t)b * S_ + srow) * H_ + h * 64 + nf * 16 + g * 4] = pk;
  }
}

// ---------------------------------------------------------------- launch
extern "C" void kernel_launch(void* const* d_in, const int* in_sizes, int n_in,
                              void* d_out, int out_size, void* d_ws, size_t ws_size,
                              hipStream_t stream) {
  const float* x  = (const float*)d_in[0];
  const float* Wq = (const float*)d_in[1];
  const float* Wk = (const float*)d_in[2];
  const float* Wv = (const float*)d_in[3];
  const float* Wo = (const float*)d_in[4];

  char* ws = (char*)d_ws;
  size_t off = 0;
  ushort* xb   = (ushort*)(ws + off); off += (size_t)M_ * H_ * 2;
  ushort* Wqkv = (ushort*)(ws + off); off += (size_t)3 * H_ * H_ * 2;
  ushort* Wob  = (ushort*)(ws + off); off += (size_t)H_ * H_ * 2;
  float*  ct   = (float*)(ws + off);  off += (size_t)S_ * 32 * 4;
  float*  st   = (float*)(ws + off);  off += (size_t)S_ * 32 * 4;
  ushort* QKV  = (ushort*)(ws + off); off += (size_t)M_ * 3 * H_ * 2;
  ushort* qb   = (ushort*)(ws + off); off += (size_t)M_ * H_ * 2;
  ushort* kb   = (ushort*)(ws + off); off += (size_t)M_ * H_ * 2;
  ushort* vtb  = (ushort*)(ws + off); off += (size_t)M_ * H_ * 2;
  ushort* ctx  = (ushort*)(ws + off); off += (size_t)M_ * H_ * 2;

  cvt_f2bf<<<M_ * H_ / 1024, 256, 0, stream>>>(x, xb, M_ * H_);
  cvt_w<<<dim3(H_ * H_ / 1024, 4), 256, 0, stream>>>(Wq, Wk, Wv, Wo, Wqkv, Wob);
  build_rope_tables<<<S_ * 32 / 256, 256, 0, stream>>>(ct, st);

  gemm_bt<1><<<dim3(3 * H_ / 128, M_ / 128), 256, 0, stream>>>(
      xb, Wqkv, QKV, M_, 3 * H_, H_);
  rope_scatter<<<M_ * NH_ * 32 / 256, 256, 0, stream>>>(QKV, ct, st, qb, kb);
  transp_v<<<dim3(S_ / 64, B_ * NH_), 256, 0, stream>>>(QKV, vtb);
  flash_attn<<<dim3(S_ / 128, B_ * NH_), 512, 0, stream>>>(qb, kb, vtb, ctx);
  gemm_bt<0><<<dim3(H_ / 128, M_ / 128), 256, 0, stream>>>(
      ctx, Wob, d_out, M_, H_, H_);
}

// Round 11
// 127.089 us; speedup vs baseline: 1.9277x; 1.0738x over previous
//
#include <hip/hip_runtime.h>

#define B_  2
#define S_  2048
#define H_  1024
#define NH_ 16
#define HD_ 64
#define M_  (B_ * S_)   // 4096

typedef short  short8  __attribute__((ext_vector_type(8)));
typedef __bf16 bf16x8  __attribute__((ext_vector_type(8)));
typedef float  f32x4   __attribute__((ext_vector_type(4)));

__device__ __forceinline__ ushort f2bf(float f) {
  union { float f; unsigned u; } v; v.f = f;
  unsigned r = v.u + 0x7fffu + ((v.u >> 16) & 1u);   // RNE
  return (ushort)(r >> 16);
}
__device__ __forceinline__ float bf2f(ushort u) {
  union { unsigned u; float f; } v; v.u = ((unsigned)u) << 16;
  return v.f;
}
// packed bf16 pair via HW cvt (RNE): dst.lo=bf16(lo), dst.hi=bf16(hi)
__device__ __forceinline__ unsigned cvtpk(float lo, float hi) {
  unsigned r;
  asm("v_cvt_pk_bf16_f32 %0, %1, %2" : "=v"(r) : "v"(lo), "v"(hi));
  return r;
}

__device__ __forceinline__ void gload_lds16(const void* g, void* l) {
  __builtin_amdgcn_global_load_lds(
      (const __attribute__((address_space(1))) void*)g,
      (__attribute__((address_space(3))) void*)l, 16, 0, 0);
}

__device__ __forceinline__ f32x4 mfma_bf16(short8 a, short8 b, f32x4 c) {
  return __builtin_amdgcn_mfma_f32_16x16x32_bf16(
      __builtin_bit_cast(bf16x8, a), __builtin_bit_cast(bf16x8, b), c, 0, 0, 0);
}

// swizzled element offsets; c = 16B chunk index
__device__ __forceinline__ int swzK(int r, int c) {   // [R][64] tiles
  return r * 64 + ((c ^ (r & 7)) << 3);
}
__device__ __forceinline__ int swzV(int r, int c) {   // [R][128] tiles
  return r * 128 + ((c ^ (r & 7)) << 3);
}

// reduce over lanes {l, l^16, l^32, l^48} — known-good shfl_xor pair
__device__ __forceinline__ float redmax64(float a) {
  a = fmaxf(a, __shfl_xor(a, 16));
  a = fmaxf(a, __shfl_xor(a, 32));
  return a;
}

// ---------------------------------------------------------------- prep (fused)
// blocks [0,4096): x f32->bf16; [4096,8192): W q/k/v/o; [8192,8448): rope tables
__global__ __launch_bounds__(256)
void prep(const float* __restrict__ x, const float* __restrict__ Wq,
          const float* __restrict__ Wk, const float* __restrict__ Wv,
          const float* __restrict__ Wo, ushort* __restrict__ xb,
          ushort* __restrict__ Wqkv, ushort* __restrict__ Wob,
          float* __restrict__ ct, float* __restrict__ st) {
  int bid = blockIdx.x, t = threadIdx.x;
  if (bid < 4096) {
    int i = (bid * 256 + t) * 4;
    float4 v = *(const float4*)&x[i];
    ushort4 o;
    o.x = f2bf(v.x); o.y = f2bf(v.y); o.z = f2bf(v.z); o.w = f2bf(v.w);
    *(ushort4*)&xb[i] = o;
  } else if (bid < 8192) {
    int y = (bid - 4096) >> 10;
    const float* src = (y == 0) ? Wq : (y == 1) ? Wk : (y == 2) ? Wv : Wo;
    ushort* dst = (y == 3) ? Wob : Wqkv + (size_t)y * H_ * H_;
    int i = (((bid - 4096) & 1023) * 256 + t) * 4;
    float4 v = *(const float4*)&src[i];
    ushort4 o;
    o.x = f2bf(v.x); o.y = f2bf(v.y); o.z = f2bf(v.z); o.w = f2bf(v.w);
    *(ushort4*)&dst[i] = o;
  } else {
    int i = (bid - 8192) * 256 + t;     // < S_*32
    int pos = i >> 5, d2 = i & 31;
    float invf = powf(10000.0f, -(float)d2 / 32.0f);
    float fr = (float)pos * invf;
    ct[i] = cosf(fr);
    st[i] = sinf(fr);
  }
}

// ---------------------------------------------------------------- GEMM  C = A * B^T
// BK=64, [128][64] swzK LDS tiles (same layout/algebra as flash K tiles).
template <int OUT_BF16>
__global__ __launch_bounds__(256)
void gemm_bt(const ushort* __restrict__ A, const ushort* __restrict__ Bm,
             void* __restrict__ Cout, int Mdim, int Ndim, int Kdim) {
  __shared__ ushort As[128 * 64];
  __shared__ ushort Bs[128 * 64];
  int t = threadIdx.x;
  int w = t >> 6, l = t & 63;
  int m0 = blockIdx.y * 128, n0 = blockIdx.x * 128;
  int wr = (w >> 1) * 64, wc = (w & 1) * 64;
  int lrow = l & 15, g = l >> 4;

  f32x4 acc[4][4];
#pragma unroll
  for (int mi = 0; mi < 4; ++mi)
#pragma unroll
    for (int ni = 0; ni < 4; ++ni) acc[mi][ni] = f32x4{0.f, 0.f, 0.f, 0.f};

  for (int k0 = 0; k0 < Kdim; k0 += 64) {
    __syncthreads();
#pragma unroll
    for (int cc = 0; cc < 4; ++cc) {
      int slot = cc * 256 + t;
      int r = slot >> 3, c = slot & 7;
      int cs = (c ^ (r & 7)) << 3;
      gload_lds16(&A[(size_t)(m0 + r) * Kdim + k0 + cs], &As[slot * 8]);
      gload_lds16(&Bm[(size_t)(n0 + r) * Kdim + k0 + cs], &Bs[slot * 8]);
    }
    __syncthreads();
#pragma unroll
    for (int kk = 0; kk < 2; ++kk) {
      short8 af[4], bfr[4];
#pragma unroll
      for (int i = 0; i < 4; ++i)
        af[i] = *(const short8*)&As[swzK(wr + i * 16 + lrow, kk * 4 + g)];
#pragma unroll
      for (int i = 0; i < 4; ++i)
        bfr[i] = *(const short8*)&Bs[swzK(wc + i * 16 + lrow, kk * 4 + g)];
#pragma unroll
      for (int mi = 0; mi < 4; ++mi)
#pragma unroll
        for (int ni = 0; ni < 4; ++ni)
          acc[mi][ni] = mfma_bf16(af[mi], bfr[ni], acc[mi][ni]);
    }
  }

#pragma unroll
  for (int mi = 0; mi < 4; ++mi)
#pragma unroll
    for (int ni = 0; ni < 4; ++ni)
#pragma unroll
      for (int j = 0; j < 4; ++j) {
        int row = m0 + wr + mi * 16 + g * 4 + j;
        int col = n0 + wc + ni * 16 + lrow;
        float vv = acc[mi][ni][j];
        if (OUT_BF16)
          ((ushort*)Cout)[(size_t)row * Ndim + col] = f2bf(vv);
        else
          ((float*)Cout)[(size_t)row * Ndim + col] = vv;
      }
}

// ---------------------------------------------------------------- RoPE + scatter (q,k)
// q pre-scaled by 0.125*log2(e) so flash can use exp2.
__global__ __launch_bounds__(256)
void rope_scatter(const ushort* __restrict__ QKV, const float* __restrict__ ct,
                  const float* __restrict__ st, ushort* __restrict__ qb,
                  ushort* __restrict__ kb) {
  const float SC = 0.125f * 1.44269504f;
  int i = blockIdx.x * 256 + threadIdx.x;   // < M_*NH_*32
  int row = i >> 9;
  int rem = i & 511;
  int h = rem >> 5, d2 = rem & 31;
  int b = row >> 11, s = row & 2047;
  size_t base = (size_t)row * 3072;
  float c = ct[s * 32 + d2], sn = st[s * 32 + d2];
  size_t o = ((size_t)(b * NH_ + h) * S_ + s) * HD_;

  float x1 = bf2f(QKV[base + h * 64 + d2]);
  float x2 = bf2f(QKV[base + h * 64 + d2 + 32]);
  qb[o + d2]      = f2bf((x1 * c - x2 * sn) * SC);
  qb[o + d2 + 32] = f2bf((x2 * c + x1 * sn) * SC);

  x1 = bf2f(QKV[base + 1024 + h * 64 + d2]);
  x2 = bf2f(QKV[base + 1024 + h * 64 + d2 + 32]);
  kb[o + d2]      = f2bf(x1 * c - x2 * sn);
  kb[o + d2 + 32] = f2bf(x2 * c + x1 * sn);
}

// ---------------------------------------------------------------- V transpose
__global__ __launch_bounds__(256)
void transp_v(const ushort* __restrict__ QKV, ushort* __restrict__ vt) {
  __shared__ ushort T[64][72];
  int s0 = blockIdx.x * 64, bh = blockIdx.y;
  int b = bh >> 4, h = bh & 15;
  int t = threadIdx.x;
#pragma unroll
  for (int cc = 0; cc < 2; ++cc) {
    int slot = cc * 256 + t;
    int r = slot >> 3, c = slot & 7;
    short8 v = *(const short8*)
        &QKV[(size_t)(b * S_ + s0 + r) * 3072 + 2048 + h * 64 + c * 8];
#pragma unroll
    for (int i = 0; i < 8; ++i) T[c * 8 + i][r] = (ushort)v[i];
  }
  __syncthreads();
  ushort* dst = vt + (size_t)bh * HD_ * S_;
#pragma unroll
  for (int cc = 0; cc < 2; ++cc) {
    int slot = cc * 256 + t;
    int d = slot >> 3, c = slot & 7;
    *(short8*)&dst[(size_t)d * S_ + s0 + c * 8] = *(const short8*)&T[d][c * 8];
  }
}

// ---------------------------------------------------------------- flash attention v9
// v8 + row-sum via ones-MFMA (reuses ap fragments; removes redsum + 32 adds
// from the VALU-pressured softmax chain).
__global__ __launch_bounds__(512, 4)
void flash_attn(const ushort* __restrict__ qb, const ushort* __restrict__ kb,
                const ushort* __restrict__ vt, ushort* __restrict__ ctx) {
  __shared__ ushort Ks[2][128 * 64];   // [key][d] swizzled
  __shared__ ushort Vs[2][64 * 128];   // [d][key] swizzled
  __shared__ ushort Ps[128 * 64];      // Q staging, then P (swizzled)
  int bh = blockIdx.y;
  int qt = (blockIdx.y & 16) ? (int)blockIdx.x : (15 - (int)blockIdx.x);
  int b = bh >> 4, h = bh & 15;
  int t = threadIdx.x, w = t >> 6, l = t & 63;
  int lrow = l & 15, g = l >> 4;
  int wrow = w * 16;
  const ushort* Q = qb + (size_t)bh * S_ * HD_;
  const ushort* K = kb + (size_t)bh * S_ * HD_;
  const ushort* V = vt + (size_t)bh * HD_ * S_;   // [64][2048]

  short8 ones;
#pragma unroll
  for (int i = 0; i < 8; ++i) ones[i] = (short)0x3F80;   // bf16 1.0

  // prologue: Q (swizzled) into Ps; K/V tile 0   (512 thr -> 2 passes each)
#pragma unroll
  for (int cc = 0; cc < 2; ++cc) {
    int slot = cc * 512 + t;
    int r = slot >> 3, c = slot & 7;
    int cs = (c ^ (r & 7)) << 3;
    gload_lds16(&Q[(size_t)(qt * 128 + r) * 64 + cs], &Ps[slot * 8]);
  }
#pragma unroll
  for (int cc = 0; cc < 2; ++cc) {
    int slot = cc * 512 + t;
    int r = slot >> 3, c = slot & 7;
    int cs = (c ^ (r & 7)) << 3;
    gload_lds16(&K[(size_t)r * 64 + cs], &Ks[0][slot * 8]);
  }
#pragma unroll
  for (int cc = 0; cc < 2; ++cc) {
    int slot = cc * 512 + t;
    int r = slot >> 4, c = slot & 15;
    int cs = (c ^ (r & 7)) << 3;
    gload_lds16(&V[(size_t)r * S_ + cs], &Vs[0][slot * 8]);
  }
  __syncthreads();

  short8 aq[2];
#pragma unroll
  for (int ks = 0; ks < 2; ++ks)
    aq[ks] = *(const short8*)&Ps[swzK(wrow + lrow, ks * 4 + g)];
  __syncthreads();   // Ps now reusable for P

  float m_ = -1e30f, ls_ = 0.f;
  f32x4 O[4];
#pragma unroll
  for (int nf = 0; nf < 4; ++nf) O[nf] = f32x4{0.f, 0.f, 0.f, 0.f};

  int nkt = qt + 1;
  for (int kt = 0; kt < nkt; ++kt) {
    const ushort* Kc = Ks[kt & 1];
    const ushort* Vc = Vs[kt & 1];
    if (kt + 1 < nkt) {
      int nb = (kt + 1) & 1;
#pragma unroll
      for (int cc = 0; cc < 2; ++cc) {
        int slot = cc * 512 + t;
        int r = slot >> 3, c = slot & 7;
        int cs = (c ^ (r & 7)) << 3;
        gload_lds16(&K[(size_t)((kt + 1) * 128 + r) * 64 + cs], &Ks[nb][slot * 8]);
      }
#pragma unroll
      for (int cc = 0; cc < 2; ++cc) {
        int slot = cc * 512 + t;
        int r = slot >> 4, c = slot & 15;
        int cs = (c ^ (r & 7)) << 3;
        gload_lds16(&V[(size_t)r * S_ + (kt + 1) * 128 + cs], &Vs[nb][slot * 8]);
      }
    }

    // S^T = K Q^T : lane q = wrow+lrow; key = nf*16 + g*4 + j
    f32x4 sc[8];
#pragma unroll
    for (int nf = 0; nf < 8; ++nf) sc[nf] = f32x4{0.f, 0.f, 0.f, 0.f};
    __builtin_amdgcn_s_setprio(1);
#pragma unroll
    for (int ks = 0; ks < 2; ++ks)
#pragma unroll
      for (int nf = 0; nf < 8; ++nf) {
        short8 bk = *(const short8*)&Kc[swzK(nf * 16 + lrow, ks * 4 + g)];
        sc[nf] = mfma_bf16(bk, aq[ks], sc[nf]);
      }
    __builtin_amdgcn_s_setprio(0);

    int qbase = qt * 128 + wrow;
    if (kt * 128 + 127 > qbase) {   // wave-uniform; only the diagonal tile
      int qi = qbase + lrow;
#pragma unroll
      for (int nf = 0; nf < 8; ++nf) {
        int kbase = kt * 128 + nf * 16 + g * 4;
#pragma unroll
        for (int j = 0; j < 4; ++j)
          if (kbase + j > qi) sc[nf][j] = -1e30f;
      }
    }

    // row max: pairwise tree + 2 shuffles
    f32x4 v4 = sc[0];
#pragma unroll
    for (int nf = 1; nf < 8; ++nf)
#pragma unroll
      for (int j = 0; j < 4; ++j) v4[j] = fmaxf(v4[j], sc[nf][j]);
    float mx = redmax64(fmaxf(fmaxf(v4[0], v4[1]), fmaxf(v4[2], v4[3])));

    // defer-max (T13)
    bool nor = __all(mx <= m_ + 8.f);
    if (!nor) {
      float mnew = fmaxf(m_, mx);
      float al = exp2f(m_ - mnew);
      m_ = mnew;
      ls_ *= al;
#pragma unroll
      for (int nf = 0; nf < 4; ++nf)
#pragma unroll
        for (int j = 0; j < 4; ++j) O[nf][j] *= al;
    }

    // exp2 (row sum comes from the ones-MFMA below)
#pragma unroll
    for (int nf = 0; nf < 8; ++nf)
#pragma unroll
      for (int j = 0; j < 4; ++j) sc[nf][j] = exp2f(sc[nf][j] - m_);

    // PV in two 64-key halves through the wave-private P rows;
    // sacc accumulates the bf16-P row sum via mfma(ones, ap).
    f32x4 sacc = f32x4{0.f, 0.f, 0.f, 0.f};
#pragma unroll
    for (int half = 0; half < 2; ++half) {
      int prow = wrow + lrow;
#pragma unroll
      for (int nf2 = 0; nf2 < 4; ++nf2) {
        int nf = half * 4 + nf2;
        uint2 pk;
        pk.x = cvtpk(sc[nf][0], sc[nf][1]);
        pk.y = cvtpk(sc[nf][2], sc[nf][3]);
        // local key = nf2*16 + g*4 -> chunk nf2*2+(g>>1), +4 elems if g odd
        *(uint2*)&Ps[swzK(prow, nf2 * 2 + (g >> 1)) + (g & 1) * 4] = pk;
      }
      __builtin_amdgcn_s_setprio(1);
#pragma unroll
      for (int ks2 = 0; ks2 < 2; ++ks2) {
        short8 ap = *(const short8*)&Ps[swzK(wrow + lrow, ks2 * 4 + g)];
        sacc = mfma_bf16(ones, ap, sacc);   // row sum, replicated in all regs
#pragma unroll
        for (int nf = 0; nf < 4; ++nf) {
          short8 bv = *(const short8*)&Vc[swzV(nf * 16 + lrow, half * 8 + ks2 * 4 + g)];
          O[nf] = mfma_bf16(bv, ap, O[nf]);
        }
      }
      __builtin_amdgcn_s_setprio(0);
    }
    ls_ += sacc[0];

    __syncthreads();   // next K/V tile staged; everyone done with current
  }

  // epilogue: lane q = wrow+lrow, d = nf*16 + g*4 + j
  float inv = 1.f / ls_;
  int srow = qt * 128 + wrow + lrow;
#pragma unroll
  for (int nf = 0; nf < 4; ++nf) {
    uint2 pk;
    pk.x = cvtpk(O[nf][0] * inv, O[nf][1] * inv);
    pk.y = cvtpk(O[nf][2] * inv, O[nf][3] * inv);
    *(uint2*)&ctx[((size_t)b * S_ + srow) * H_ + h * 64 + nf * 16 + g * 4] = pk;
  }
}

// ---------------------------------------------------------------- launch
extern "C" void kernel_launch(void* const* d_in, const int* in_sizes, int n_in,
                              void* d_out, int out_size, void* d_ws, size_t ws_size,
                              hipStream_t stream) {
  const float* x  = (const float*)d_in[0];
  const float* Wq = (const float*)d_in[1];
  const float* Wk = (const float*)d_in[2];
  const float* Wv = (const float*)d_in[3];
  const float* Wo = (const float*)d_in[4];

  char* ws = (char*)d_ws;
  size_t off = 0;
  ushort* xb   = (ushort*)(ws + off); off += (size_t)M_ * H_ * 2;
  ushort* Wqkv = (ushort*)(ws + off); off += (size_t)3 * H_ * H_ * 2;
  ushort* Wob  = (ushort*)(ws + off); off += (size_t)H_ * H_ * 2;
  float*  ct   = (float*)(ws + off);  off += (size_t)S_ * 32 * 4;
  float*  st   = (float*)(ws + off);  off += (size_t)S_ * 32 * 4;
  ushort* QKV  = (ushort*)(ws + off); off += (size_t)M_ * 3 * H_ * 2;
  ushort* qb   = (ushort*)(ws + off); off += (size_t)M_ * H_ * 2;
  ushort* kb   = (ushort*)(ws + off); off += (size_t)M_ * H_ * 2;
  ushort* vtb  = (ushort*)(ws + off); off += (size_t)M_ * H_ * 2;
  ushort* ctx  = (ushort*)(ws + off); off += (size_t)M_ * H_ * 2;

  prep<<<8448, 256, 0, stream>>>(x, Wq, Wk, Wv, Wo, xb, Wqkv, Wob, ct, st);

  gemm_bt<1><<<dim3(3 * H_ / 128, M_ / 128), 256, 0, stream>>>(
      xb, Wqkv, QKV, M_, 3 * H_, H_);
  rope_scatter<<<M_ * NH_ * 32 / 256, 256, 0, stream>>>(QKV, ct, st, qb, kb);
  transp_v<<<dim3(S_ / 64, B_ * NH_), 256, 0, stream>>>(QKV, vtb);
  flash_attn<<<dim3(S_ / 128, B_ * NH_), 512, 0, stream>>>(qb, kb, vtb, ctx);
  gemm_bt<0><<<dim3(H_ / 128, M_ / 128), 256, 0, stream>>>(
      ctx, Wob, d_out, M_, H_, H_);
}

// Round 12
// 122.151 us; speedup vs baseline: 2.0056x; 1.0404x over previous
//
#include <hip/hip_runtime.h>

#define B_  2
#define S_  2048
#define H_  1024
#define NH_ 16
#define HD_ 64
#define M_  (B_ * S_)   // 4096

typedef short  short8  __attribute__((ext_vector_type(8)));
typedef __bf16 bf16x8  __attribute__((ext_vector_type(8)));
typedef float  f32x4   __attribute__((ext_vector_type(4)));

__device__ __forceinline__ ushort f2bf(float f) {
  union { float f; unsigned u; } v; v.f = f;
  unsigned r = v.u + 0x7fffu + ((v.u >> 16) & 1u);   // RNE
  return (ushort)(r >> 16);
}
__device__ __forceinline__ float bf2f(ushort u) {
  union { unsigned u; float f; } v; v.u = ((unsigned)u) << 16;
  return v.f;
}
// packed bf16 pair via HW cvt (RNE): dst.lo=bf16(lo), dst.hi=bf16(hi)
__device__ __forceinline__ unsigned cvtpk(float lo, float hi) {
  unsigned r;
  asm("v_cvt_pk_bf16_f32 %0, %1, %2" : "=v"(r) : "v"(lo), "v"(hi));
  return r;
}

__device__ __forceinline__ void gload_lds16(const void* g, void* l) {
  __builtin_amdgcn_global_load_lds(
      (const __attribute__((address_space(1))) void*)g,
      (__attribute__((address_space(3))) void*)l, 16, 0, 0);
}

__device__ __forceinline__ f32x4 mfma_bf16(short8 a, short8 b, f32x4 c) {
  return __builtin_amdgcn_mfma_f32_16x16x32_bf16(
      __builtin_bit_cast(bf16x8, a), __builtin_bit_cast(bf16x8, b), c, 0, 0, 0);
}

// swizzled element offsets; c = 16B chunk index
__device__ __forceinline__ int swzK(int r, int c) {   // [R][64] tiles
  return r * 64 + ((c ^ (r & 7)) << 3);
}
__device__ __forceinline__ int swzV(int r, int c) {   // [R][128] tiles
  return r * 128 + ((c ^ (r & 7)) << 3);
}

// reduce over lanes {l, l^16, l^32, l^48} — known-good shfl_xor pair
__device__ __forceinline__ float redmax64(float a) {
  a = fmaxf(a, __shfl_xor(a, 16));
  a = fmaxf(a, __shfl_xor(a, 32));
  return a;
}

// ---------------------------------------------------------------- prep (fused)
// blocks [0,4096): x f32->bf16; [4096,8192): W q/k/v/o; [8192,8448): rope tables
__global__ __launch_bounds__(256)
void prep(const float* __restrict__ x, const float* __restrict__ Wq,
          const float* __restrict__ Wk, const float* __restrict__ Wv,
          const float* __restrict__ Wo, ushort* __restrict__ xb,
          ushort* __restrict__ Wqkv, ushort* __restrict__ Wob,
          float* __restrict__ ct, float* __restrict__ st) {
  int bid = blockIdx.x, t = threadIdx.x;
  if (bid < 4096) {
    int i = (bid * 256 + t) * 4;
    float4 v = *(const float4*)&x[i];
    ushort4 o;
    o.x = f2bf(v.x); o.y = f2bf(v.y); o.z = f2bf(v.z); o.w = f2bf(v.w);
    *(ushort4*)&xb[i] = o;
  } else if (bid < 8192) {
    int y = (bid - 4096) >> 10;
    const float* src = (y == 0) ? Wq : (y == 1) ? Wk : (y == 2) ? Wv : Wo;
    ushort* dst = (y == 3) ? Wob : Wqkv + (size_t)y * H_ * H_;
    int i = (((bid - 4096) & 1023) * 256 + t) * 4;
    float4 v = *(const float4*)&src[i];
    ushort4 o;
    o.x = f2bf(v.x); o.y = f2bf(v.y); o.z = f2bf(v.z); o.w = f2bf(v.w);
    *(ushort4*)&dst[i] = o;
  } else {
    int i = (bid - 8192) * 256 + t;     // < S_*32
    int pos = i >> 5, d2 = i & 31;
    float invf = powf(10000.0f, -(float)d2 / 32.0f);
    float fr = (float)pos * invf;
    ct[i] = cosf(fr);
    st[i] = sinf(fr);
  }
}

// ---------------------------------------------------------------- GEMM  C = A * B^T
// BK=64, [128][64] swzK LDS tiles (same layout/algebra as flash K tiles).
template <int OUT_BF16>
__global__ __launch_bounds__(256)
void gemm_bt(const ushort* __restrict__ A, const ushort* __restrict__ Bm,
             void* __restrict__ Cout, int Mdim, int Ndim, int Kdim) {
  __shared__ ushort As[128 * 64];
  __shared__ ushort Bs[128 * 64];
  int t = threadIdx.x;
  int w = t >> 6, l = t & 63;
  int m0 = blockIdx.y * 128, n0 = blockIdx.x * 128;
  int wr = (w >> 1) * 64, wc = (w & 1) * 64;
  int lrow = l & 15, g = l >> 4;

  f32x4 acc[4][4];
#pragma unroll
  for (int mi = 0; mi < 4; ++mi)
#pragma unroll
    for (int ni = 0; ni < 4; ++ni) acc[mi][ni] = f32x4{0.f, 0.f, 0.f, 0.f};

  for (int k0 = 0; k0 < Kdim; k0 += 64) {
    __syncthreads();
#pragma unroll
    for (int cc = 0; cc < 4; ++cc) {
      int slot = cc * 256 + t;
      int r = slot >> 3, c = slot & 7;
      int cs = (c ^ (r & 7)) << 3;
      gload_lds16(&A[(size_t)(m0 + r) * Kdim + k0 + cs], &As[slot * 8]);
      gload_lds16(&Bm[(size_t)(n0 + r) * Kdim + k0 + cs], &Bs[slot * 8]);
    }
    __syncthreads();
#pragma unroll
    for (int kk = 0; kk < 2; ++kk) {
      short8 af[4], bfr[4];
#pragma unroll
      for (int i = 0; i < 4; ++i)
        af[i] = *(const short8*)&As[swzK(wr + i * 16 + lrow, kk * 4 + g)];
#pragma unroll
      for (int i = 0; i < 4; ++i)
        bfr[i] = *(const short8*)&Bs[swzK(wc + i * 16 + lrow, kk * 4 + g)];
#pragma unroll
      for (int mi = 0; mi < 4; ++mi)
#pragma unroll
        for (int ni = 0; ni < 4; ++ni)
          acc[mi][ni] = mfma_bf16(af[mi], bfr[ni], acc[mi][ni]);
    }
  }

#pragma unroll
  for (int mi = 0; mi < 4; ++mi)
#pragma unroll
    for (int ni = 0; ni < 4; ++ni)
#pragma unroll
      for (int j = 0; j < 4; ++j) {
        int row = m0 + wr + mi * 16 + g * 4 + j;
        int col = n0 + wc + ni * 16 + lrow;
        float vv = acc[mi][ni][j];
        if (OUT_BF16)
          ((ushort*)Cout)[(size_t)row * Ndim + col] = f2bf(vv);
        else
          ((float*)Cout)[(size_t)row * Ndim + col] = vv;
      }
}

// ---------------------------------------------------------------- RoPE + scatter (q,k)
// q pre-scaled by 0.125*log2(e) so flash can use exp2.
__global__ __launch_bounds__(256)
void rope_scatter(const ushort* __restrict__ QKV, const float* __restrict__ ct,
                  const float* __restrict__ st, ushort* __restrict__ qb,
                  ushort* __restrict__ kb) {
  const float SC = 0.125f * 1.44269504f;
  int i = blockIdx.x * 256 + threadIdx.x;   // < M_*NH_*32
  int row = i >> 9;
  int rem = i & 511;
  int h = rem >> 5, d2 = rem & 31;
  int b = row >> 11, s = row & 2047;
  size_t base = (size_t)row * 3072;
  float c = ct[s * 32 + d2], sn = st[s * 32 + d2];
  size_t o = ((size_t)(b * NH_ + h) * S_ + s) * HD_;

  float x1 = bf2f(QKV[base + h * 64 + d2]);
  float x2 = bf2f(QKV[base + h * 64 + d2 + 32]);
  qb[o + d2]      = f2bf((x1 * c - x2 * sn) * SC);
  qb[o + d2 + 32] = f2bf((x2 * c + x1 * sn) * SC);

  x1 = bf2f(QKV[base + 1024 + h * 64 + d2]);
  x2 = bf2f(QKV[base + 1024 + h * 64 + d2 + 32]);
  kb[o + d2]      = f2bf(x1 * c - x2 * sn);
  kb[o + d2 + 32] = f2bf(x2 * c + x1 * sn);
}

// ---------------------------------------------------------------- V transpose
__global__ __launch_bounds__(256)
void transp_v(const ushort* __restrict__ QKV, ushort* __restrict__ vt) {
  __shared__ ushort T[64][72];
  int s0 = blockIdx.x * 64, bh = blockIdx.y;
  int b = bh >> 4, h = bh & 15;
  int t = threadIdx.x;
#pragma unroll
  for (int cc = 0; cc < 2; ++cc) {
    int slot = cc * 256 + t;
    int r = slot >> 3, c = slot & 7;
    short8 v = *(const short8*)
        &QKV[(size_t)(b * S_ + s0 + r) * 3072 + 2048 + h * 64 + c * 8];
#pragma unroll
    for (int i = 0; i < 8; ++i) T[c * 8 + i][r] = (ushort)v[i];
  }
  __syncthreads();
  ushort* dst = vt + (size_t)bh * HD_ * S_;
#pragma unroll
  for (int cc = 0; cc < 2; ++cc) {
    int slot = cc * 256 + t;
    int d = slot >> 3, c = slot & 7;
    *(short8*)&dst[(size_t)d * S_ + s0 + c * 8] = *(const short8*)&T[d][c * 8];
  }
}

// ---------------------------------------------------------------- flash attention v10
// 64 KB LDS -> 2 blocks/CU (16 waves). Q direct-to-reg; K single-buffered
// (staged post-QK-barrier, hidden under softmax+PV); V double-buffered.
__global__ __launch_bounds__(512, 4)
void flash_attn(const ushort* __restrict__ qb, const ushort* __restrict__ kb,
                const ushort* __restrict__ vt, ushort* __restrict__ ctx) {
  __shared__ ushort Ks[128 * 64];      // [key][d] swizzled, single buffer
  __shared__ ushort Vs[2][64 * 128];   // [d][key] swizzled, double buffer
  __shared__ ushort Ps[128 * 64];      // P (swizzled), wave-private rows
  int bh = blockIdx.y;
  int qt = (blockIdx.y & 16) ? (int)blockIdx.x : (15 - (int)blockIdx.x);
  int b = bh >> 4, h = bh & 15;
  int t = threadIdx.x, w = t >> 6, l = t & 63;
  int lrow = l & 15, g = l >> 4;
  int wrow = w * 16;
  const ushort* Q = qb + (size_t)bh * S_ * HD_;
  const ushort* K = kb + (size_t)bh * S_ * HD_;
  const ushort* V = vt + (size_t)bh * HD_ * S_;   // [64][2048]

  short8 ones;
#pragma unroll
  for (int i = 0; i < 8; ++i) ones[i] = (short)0x3F80;   // bf16 1.0

  // prologue: K/V tile 0 -> LDS; Q -> registers
#pragma unroll
  for (int cc = 0; cc < 2; ++cc) {
    int slot = cc * 512 + t;
    int r = slot >> 3, c = slot & 7;
    int cs = (c ^ (r & 7)) << 3;
    gload_lds16(&K[(size_t)r * 64 + cs], &Ks[slot * 8]);
  }
#pragma unroll
  for (int cc = 0; cc < 2; ++cc) {
    int slot = cc * 512 + t;
    int r = slot >> 4, c = slot & 15;
    int cs = (c ^ (r & 7)) << 3;
    gload_lds16(&V[(size_t)r * S_ + cs], &Vs[0][slot * 8]);
  }
  short8 aq[2];
  {
    int qrow = qt * 128 + wrow + lrow;
#pragma unroll
    for (int ks = 0; ks < 2; ++ks)
      aq[ks] = *(const short8*)&Q[(size_t)qrow * 64 + ks * 32 + g * 8];
  }
  __syncthreads();

  float m_ = -1e30f, ls_ = 0.f;
  f32x4 O[4];
#pragma unroll
  for (int nf = 0; nf < 4; ++nf) O[nf] = f32x4{0.f, 0.f, 0.f, 0.f};

  int nkt = qt + 1;
  for (int kt = 0; kt < nkt; ++kt) {
    const ushort* Vc = Vs[kt & 1];

    // S^T = K Q^T : lane q = wrow+lrow; key = nf*16 + g*4 + j
    f32x4 sc[8];
#pragma unroll
    for (int nf = 0; nf < 8; ++nf) sc[nf] = f32x4{0.f, 0.f, 0.f, 0.f};
    __builtin_amdgcn_s_setprio(1);
#pragma unroll
    for (int ks = 0; ks < 2; ++ks)
#pragma unroll
      for (int nf = 0; nf < 8; ++nf) {
        short8 bk = *(const short8*)&Ks[swzK(nf * 16 + lrow, ks * 4 + g)];
        sc[nf] = mfma_bf16(bk, aq[ks], sc[nf]);
      }
    __builtin_amdgcn_s_setprio(0);

    __syncthreads();   // all waves done reading Ks; nothing else in flight

    // stage K/V for kt+1 (async; lands during softmax+PV below)
    if (kt + 1 < nkt) {
      int nb = (kt + 1) & 1;
#pragma unroll
      for (int cc = 0; cc < 2; ++cc) {
        int slot = cc * 512 + t;
        int r = slot >> 3, c = slot & 7;
        int cs = (c ^ (r & 7)) << 3;
        gload_lds16(&K[(size_t)((kt + 1) * 128 + r) * 64 + cs], &Ks[slot * 8]);
      }
#pragma unroll
      for (int cc = 0; cc < 2; ++cc) {
        int slot = cc * 512 + t;
        int r = slot >> 4, c = slot & 15;
        int cs = (c ^ (r & 7)) << 3;
        gload_lds16(&V[(size_t)r * S_ + (kt + 1) * 128 + cs], &Vs[nb][slot * 8]);
      }
    }

    int qbase = qt * 128 + wrow;
    if (kt * 128 + 127 > qbase) {   // wave-uniform; only the diagonal tile
      int qi = qbase + lrow;
#pragma unroll
      for (int nf = 0; nf < 8; ++nf) {
        int kbase = kt * 128 + nf * 16 + g * 4;
#pragma unroll
        for (int j = 0; j < 4; ++j)
          if (kbase + j > qi) sc[nf][j] = -1e30f;
      }
    }

    // row max: pairwise tree + 2 shuffles
    f32x4 v4 = sc[0];
#pragma unroll
    for (int nf = 1; nf < 8; ++nf)
#pragma unroll
      for (int j = 0; j < 4; ++j) v4[j] = fmaxf(v4[j], sc[nf][j]);
    float mx = redmax64(fmaxf(fmaxf(v4[0], v4[1]), fmaxf(v4[2], v4[3])));

    // defer-max (T13)
    bool nor = __all(mx <= m_ + 8.f);
    if (!nor) {
      float mnew = fmaxf(m_, mx);
      float al = exp2f(m_ - mnew);
      m_ = mnew;
      ls_ *= al;
#pragma unroll
      for (int nf = 0; nf < 4; ++nf)
#pragma unroll
        for (int j = 0; j < 4; ++j) O[nf][j] *= al;
    }

    // exp2 (row sum comes from the ones-MFMA below)
#pragma unroll
    for (int nf = 0; nf < 8; ++nf)
#pragma unroll
      for (int j = 0; j < 4; ++j) sc[nf][j] = exp2f(sc[nf][j] - m_);

    // PV in two 64-key halves through the wave-private P rows;
    // sacc accumulates the bf16-P row sum via mfma(ones, ap).
    f32x4 sacc = f32x4{0.f, 0.f, 0.f, 0.f};
#pragma unroll
    for (int half = 0; half < 2; ++half) {
      int prow = wrow + lrow;
#pragma unroll
      for (int nf2 = 0; nf2 < 4; ++nf2) {
        int nf = half * 4 + nf2;
        uint2 pk;
        pk.x = cvtpk(sc[nf][0], sc[nf][1]);
        pk.y = cvtpk(sc[nf][2], sc[nf][3]);
        // local key = nf2*16 + g*4 -> chunk nf2*2+(g>>1), +4 elems if g odd
        *(uint2*)&Ps[swzK(prow, nf2 * 2 + (g >> 1)) + (g & 1) * 4] = pk;
      }
      __builtin_amdgcn_s_setprio(1);
#pragma unroll
      for (int ks2 = 0; ks2 < 2; ++ks2) {
        short8 ap = *(const short8*)&Ps[swzK(wrow + lrow, ks2 * 4 + g)];
        sacc = mfma_bf16(ones, ap, sacc);   // row sum, replicated in all regs
#pragma unroll
        for (int nf = 0; nf < 4; ++nf) {
          short8 bv = *(const short8*)&Vc[swzV(nf * 16 + lrow, half * 8 + ks2 * 4 + g)];
          O[nf] = mfma_bf16(bv, ap, O[nf]);
        }
      }
      __builtin_amdgcn_s_setprio(0);
    }
    ls_ += sacc[0];

    __syncthreads();   // staging drained; K/V ready for kt+1
  }

  // epilogue: lane q = wrow+lrow, d = nf*16 + g*4 + j
  float inv = 1.f / ls_;
  int srow = qt * 128 + wrow + lrow;
#pragma unroll
  for (int nf = 0; nf < 4; ++nf) {
    uint2 pk;
    pk.x = cvtpk(O[nf][0] * inv, O[nf][1] * inv);
    pk.y = cvtpk(O[nf][2] * inv, O[nf][3] * inv);
    *(uint2*)&ctx[((size_t)b * S_ + srow) * H_ + h * 64 + nf * 16 + g * 4] = pk;
  }
}

// ---------------------------------------------------------------- launch
extern "C" void kernel_launch(void* const* d_in, const int* in_sizes, int n_in,
                              void* d_out, int out_size, void* d_ws, size_t ws_size,
                              hipStream_t stream) {
  const float* x  = (const float*)d_in[0];
  const float* Wq = (const float*)d_in[1];
  const float* Wk = (const float*)d_in[2];
  const float* Wv = (const float*)d_in[3];
  const float* Wo = (const float*)d_in[4];

  char* ws = (char*)d_ws;
  size_t off = 0;
  ushort* xb   = (ushort*)(ws + off); off += (size_t)M_ * H_ * 2;
  ushort* Wqkv = (ushort*)(ws + off); off += (size_t)3 * H_ * H_ * 2;
  ushort* Wob  = (ushort*)(ws + off); off += (size_t)H_ * H_ * 2;
  float*  ct   = (float*)(ws + off);  off += (size_t)S_ * 32 * 4;
  float*  st   = (float*)(ws + off);  off += (size_t)S_ * 32 * 4;
  ushort* QKV  = (ushort*)(ws + off); off += (size_t)M_ * 3 * H_ * 2;
  ushort* qb   = (ushort*)(ws + off); off += (size_t)M_ * H_ * 2;
  ushort* kb   = (ushort*)(ws + off); off += (size_t)M_ * H_ * 2;
  ushort* vtb  = (ushort*)(ws + off); off += (size_t)M_ * H_ * 2;
  ushort* ctx  = (ushort*)(ws + off); off += (size_t)M_ * H_ * 2;

  prep<<<8448, 256, 0, stream>>>(x, Wq, Wk, Wv, Wo, xb, Wqkv, Wob, ct, st);

  gemm_bt<1><<<dim3(3 * H_ / 128, M_ / 128), 256, 0, stream>>>(
      xb, Wqkv, QKV, M_, 3 * H_, H_);
  rope_scatter<<<M_ * NH_ * 32 / 256, 256, 0, stream>>>(QKV, ct, st, qb, kb);
  transp_v<<<dim3(S_ / 64, B_ * NH_), 256, 0, stream>>>(QKV, vtb);
  flash_attn<<<dim3(S_ / 128, B_ * NH_), 512, 0, stream>>>(qb, kb, vtb, ctx);
  gemm_bt<0><<<dim3(H_ / 128, M_ / 128), 256, 0, stream>>>(
      ctx, Wob, d_out, M_, H_, H_);
}

// Round 13
// 120.372 us; speedup vs baseline: 2.0352x; 1.0148x over previous
//
#include <hip/hip_runtime.h>

#define B_  2
#define S_  2048
#define H_  1024
#define NH_ 16
#define HD_ 64
#define M_  (B_ * S_)   // 4096

typedef short  short8  __attribute__((ext_vector_type(8)));
typedef __bf16 bf16x8  __attribute__((ext_vector_type(8)));
typedef float  f32x4   __attribute__((ext_vector_type(4)));

__device__ __forceinline__ ushort f2bf(float f) {
  union { float f; unsigned u; } v; v.f = f;
  unsigned r = v.u + 0x7fffu + ((v.u >> 16) & 1u);   // RNE
  return (ushort)(r >> 16);
}
__device__ __forceinline__ float bf2f(ushort u) {
  union { unsigned u; float f; } v; v.u = ((unsigned)u) << 16;
  return v.f;
}
// packed bf16 pair via HW cvt (RNE): dst.lo=bf16(lo), dst.hi=bf16(hi)
__device__ __forceinline__ unsigned cvtpk(float lo, float hi) {
  unsigned r;
  asm("v_cvt_pk_bf16_f32 %0, %1, %2" : "=v"(r) : "v"(lo), "v"(hi));
  return r;
}

__device__ __forceinline__ void gload_lds16(const void* g, void* l) {
  __builtin_amdgcn_global_load_lds(
      (const __attribute__((address_space(1))) void*)g,
      (__attribute__((address_space(3))) void*)l, 16, 0, 0);
}

__device__ __forceinline__ f32x4 mfma_bf16(short8 a, short8 b, f32x4 c) {
  return __builtin_amdgcn_mfma_f32_16x16x32_bf16(
      __builtin_bit_cast(bf16x8, a), __builtin_bit_cast(bf16x8, b), c, 0, 0, 0);
}

// swizzled element offsets; c = 16B chunk index
__device__ __forceinline__ int swzK(int r, int c) {   // [R][64] tiles
  return r * 64 + ((c ^ (r & 7)) << 3);
}
__device__ __forceinline__ int swzV(int r, int c) {   // [R][128] tiles
  return r * 128 + ((c ^ (r & 7)) << 3);
}

// reduce over lanes {l, l^16, l^32, l^48} — known-good shfl_xor pair
__device__ __forceinline__ float redmax64(float a) {
  a = fmaxf(a, __shfl_xor(a, 16));
  a = fmaxf(a, __shfl_xor(a, 32));
  return a;
}

// ---------------------------------------------------------------- prep (fused)
// blocks [0,4096): x f32->bf16; [4096,8192): W q/k/v/o; [8192,8448): rope tables
__global__ __launch_bounds__(256)
void prep(const float* __restrict__ x, const float* __restrict__ Wq,
          const float* __restrict__ Wk, const float* __restrict__ Wv,
          const float* __restrict__ Wo, ushort* __restrict__ xb,
          ushort* __restrict__ Wqkv, ushort* __restrict__ Wob,
          float* __restrict__ ct, float* __restrict__ st) {
  int bid = blockIdx.x, t = threadIdx.x;
  if (bid < 4096) {
    int i = (bid * 256 + t) * 4;
    float4 v = *(const float4*)&x[i];
    ushort4 o;
    o.x = f2bf(v.x); o.y = f2bf(v.y); o.z = f2bf(v.z); o.w = f2bf(v.w);
    *(ushort4*)&xb[i] = o;
  } else if (bid < 8192) {
    int y = (bid - 4096) >> 10;
    const float* src = (y == 0) ? Wq : (y == 1) ? Wk : (y == 2) ? Wv : Wo;
    ushort* dst = (y == 3) ? Wob : Wqkv + (size_t)y * H_ * H_;
    int i = (((bid - 4096) & 1023) * 256 + t) * 4;
    float4 v = *(const float4*)&src[i];
    ushort4 o;
    o.x = f2bf(v.x); o.y = f2bf(v.y); o.z = f2bf(v.z); o.w = f2bf(v.w);
    *(ushort4*)&dst[i] = o;
  } else {
    int i = (bid - 8192) * 256 + t;     // < S_*32
    int pos = i >> 5, d2 = i & 31;
    float invf = powf(10000.0f, -(float)d2 / 32.0f);
    float fr = (float)pos * invf;
    ct[i] = cosf(fr);
    st[i] = sinf(fr);
  }
}

// ---------------------------------------------------------------- GEMM  C = A * B^T
// BK=64, [128][64] swzK LDS tiles.
// MODE 0: C f32 row-major.
// MODE 2: fused QKV epilogue — RoPE q/k (f32, in-lane pairs ni<->ni+2) and
//         scatter to qb/kb (b,h,s,d); V transposed in-register to vt[bh][d][s].
template <int MODE>
__global__ __launch_bounds__(256)
void gemm_bt(const ushort* __restrict__ A, const ushort* __restrict__ Bm,
             void* __restrict__ Cout, int Mdim, int Ndim, int Kdim,
             const float* __restrict__ ct, const float* __restrict__ st,
             ushort* __restrict__ qb, ushort* __restrict__ kb,
             ushort* __restrict__ vt) {
  __shared__ ushort As[128 * 64];
  __shared__ ushort Bs[128 * 64];
  int t = threadIdx.x;
  int w = t >> 6, l = t & 63;
  int m0 = blockIdx.y * 128, n0 = blockIdx.x * 128;
  int wr = (w >> 1) * 64, wc = (w & 1) * 64;
  int lrow = l & 15, g = l >> 4;

  f32x4 acc[4][4];
#pragma unroll
  for (int mi = 0; mi < 4; ++mi)
#pragma unroll
    for (int ni = 0; ni < 4; ++ni) acc[mi][ni] = f32x4{0.f, 0.f, 0.f, 0.f};

  for (int k0 = 0; k0 < Kdim; k0 += 64) {
    __syncthreads();
#pragma unroll
    for (int cc = 0; cc < 4; ++cc) {
      int slot = cc * 256 + t;
      int r = slot >> 3, c = slot & 7;
      int cs = (c ^ (r & 7)) << 3;
      gload_lds16(&A[(size_t)(m0 + r) * Kdim + k0 + cs], &As[slot * 8]);
      gload_lds16(&Bm[(size_t)(n0 + r) * Kdim + k0 + cs], &Bs[slot * 8]);
    }
    __syncthreads();
#pragma unroll
    for (int kk = 0; kk < 2; ++kk) {
      short8 af[4], bfr[4];
#pragma unroll
      for (int i = 0; i < 4; ++i)
        af[i] = *(const short8*)&As[swzK(wr + i * 16 + lrow, kk * 4 + g)];
#pragma unroll
      for (int i = 0; i < 4; ++i)
        bfr[i] = *(const short8*)&Bs[swzK(wc + i * 16 + lrow, kk * 4 + g)];
#pragma unroll
      for (int mi = 0; mi < 4; ++mi)
#pragma unroll
        for (int ni = 0; ni < 4; ++ni)
          acc[mi][ni] = mfma_bf16(af[mi], bfr[ni], acc[mi][ni]);
    }
  }

  if (MODE == 0) {
#pragma unroll
    for (int mi = 0; mi < 4; ++mi)
#pragma unroll
      for (int ni = 0; ni < 4; ++ni)
#pragma unroll
        for (int j = 0; j < 4; ++j) {
          int row = m0 + wr + mi * 16 + g * 4 + j;
          int col = n0 + wc + ni * 16 + lrow;
          ((float*)Cout)[(size_t)row * Ndim + col] = acc[mi][ni][j];
        }
  } else {
    // wave's 64 cols = one head; tiles never straddle q/k/v boundaries
    int colbase = n0 + wc;
    int sector = colbase >> 10;          // 0=q, 1=k, 2=v (wave-uniform)
    int h = (colbase & 1023) >> 6;
    if (sector < 2) {
      ushort* dst = (sector == 0) ? qb : kb;
      const float SCq = (sector == 0) ? 0.125f * 1.44269504f : 1.0f;
#pragma unroll
      for (int mi = 0; mi < 4; ++mi)
#pragma unroll
        for (int j = 0; j < 4; ++j) {
          int row = m0 + wr + mi * 16 + g * 4 + j;
          int b = row >> 11, s = row & 2047;
          size_t o = ((size_t)(b * NH_ + h) * S_ + s) * HD_;
          float c0 = ct[s * 32 + lrow],      s0 = st[s * 32 + lrow];
          float c1 = ct[s * 32 + 16 + lrow], s1 = st[s * 32 + 16 + lrow];
          float x1a = acc[mi][0][j], x2a = acc[mi][2][j];   // d = lrow, lrow+32
          float x1b = acc[mi][1][j], x2b = acc[mi][3][j];   // d = 16+lrow, 48+lrow
          dst[o + lrow]      = f2bf((x1a * c0 - x2a * s0) * SCq);
          dst[o + lrow + 32] = f2bf((x2a * c0 + x1a * s0) * SCq);
          dst[o + lrow + 16] = f2bf((x1b * c1 - x2b * s1) * SCq);
          dst[o + lrow + 48] = f2bf((x2b * c1 + x1b * s1) * SCq);
        }
    } else {
#pragma unroll
      for (int mi = 0; mi < 4; ++mi) {
        int row0 = m0 + wr + mi * 16 + g * 4;   // 4 consecutive s, same b
        int b = row0 >> 11, s0r = row0 & 2047;
        size_t obase = (size_t)(b * NH_ + h) * HD_ * S_;
#pragma unroll
        for (int ni = 0; ni < 4; ++ni) {
          int d = ni * 16 + lrow;
          uint2 pk;
          pk.x = cvtpk(acc[mi][ni][0], acc[mi][ni][1]);
          pk.y = cvtpk(acc[mi][ni][2], acc[mi][ni][3]);
          *(uint2*)&vt[obase + (size_t)d * S_ + s0r] = pk;
        }
      }
    }
  }
}

// ---------------------------------------------------------------- flash attention v10
// 64 KB LDS; Q direct-to-reg; K single-buffered (staged post-QK-barrier,
// hidden under softmax+PV); V double-buffered.
__global__ __launch_bounds__(512, 4)
void flash_attn(const ushort* __restrict__ qb, const ushort* __restrict__ kb,
                const ushort* __restrict__ vt, ushort* __restrict__ ctx) {
  __shared__ ushort Ks[128 * 64];      // [key][d] swizzled, single buffer
  __shared__ ushort Vs[2][64 * 128];   // [d][key] swizzled, double buffer
  __shared__ ushort Ps[128 * 64];      // P (swizzled), wave-private rows
  int bh = blockIdx.y;
  int qt = (blockIdx.y & 16) ? (int)blockIdx.x : (15 - (int)blockIdx.x);
  int b = bh >> 4, h = bh & 15;
  int t = threadIdx.x, w = t >> 6, l = t & 63;
  int lrow = l & 15, g = l >> 4;
  int wrow = w * 16;
  const ushort* Q = qb + (size_t)bh * S_ * HD_;
  const ushort* K = kb + (size_t)bh * S_ * HD_;
  const ushort* V = vt + (size_t)bh * HD_ * S_;   // [64][2048]

  short8 ones;
#pragma unroll
  for (int i = 0; i < 8; ++i) ones[i] = (short)0x3F80;   // bf16 1.0

  // prologue: K/V tile 0 -> LDS; Q -> registers
#pragma unroll
  for (int cc = 0; cc < 2; ++cc) {
    int slot = cc * 512 + t;
    int r = slot >> 3, c = slot & 7;
    int cs = (c ^ (r & 7)) << 3;
    gload_lds16(&K[(size_t)r * 64 + cs], &Ks[slot * 8]);
  }
#pragma unroll
  for (int cc = 0; cc < 2; ++cc) {
    int slot = cc * 512 + t;
    int r = slot >> 4, c = slot & 15;
    int cs = (c ^ (r & 7)) << 3;
    gload_lds16(&V[(size_t)r * S_ + cs], &Vs[0][slot * 8]);
  }
  short8 aq[2];
  {
    int qrow = qt * 128 + wrow + lrow;
#pragma unroll
    for (int ks = 0; ks < 2; ++ks)
      aq[ks] = *(const short8*)&Q[(size_t)qrow * 64 + ks * 32 + g * 8];
  }
  __syncthreads();

  float m_ = -1e30f, ls_ = 0.f;
  f32x4 O[4];
#pragma unroll
  for (int nf = 0; nf < 4; ++nf) O[nf] = f32x4{0.f, 0.f, 0.f, 0.f};

  int nkt = qt + 1;
  for (int kt = 0; kt < nkt; ++kt) {
    const ushort* Vc = Vs[kt & 1];

    // S^T = K Q^T : lane q = wrow+lrow; key = nf*16 + g*4 + j
    f32x4 sc[8];
#pragma unroll
    for (int nf = 0; nf < 8; ++nf) sc[nf] = f32x4{0.f, 0.f, 0.f, 0.f};
    __builtin_amdgcn_s_setprio(1);
#pragma unroll
    for (int ks = 0; ks < 2; ++ks)
#pragma unroll
      for (int nf = 0; nf < 8; ++nf) {
        short8 bk = *(const short8*)&Ks[swzK(nf * 16 + lrow, ks * 4 + g)];
        sc[nf] = mfma_bf16(bk, aq[ks], sc[nf]);
      }
    __builtin_amdgcn_s_setprio(0);

    __syncthreads();   // all waves done reading Ks; nothing else in flight

    // stage K/V for kt+1 (async; lands during softmax+PV below)
    if (kt + 1 < nkt) {
      int nb = (kt + 1) & 1;
#pragma unroll
      for (int cc = 0; cc < 2; ++cc) {
        int slot = cc * 512 + t;
        int r = slot >> 3, c = slot & 7;
        int cs = (c ^ (r & 7)) << 3;
        gload_lds16(&K[(size_t)((kt + 1) * 128 + r) * 64 + cs], &Ks[slot * 8]);
      }
#pragma unroll
      for (int cc = 0; cc < 2; ++cc) {
        int slot = cc * 512 + t;
        int r = slot >> 4, c = slot & 15;
        int cs = (c ^ (r & 7)) << 3;
        gload_lds16(&V[(size_t)r * S_ + (kt + 1) * 128 + cs], &Vs[nb][slot * 8]);
      }
    }

    int qbase = qt * 128 + wrow;
    if (kt * 128 + 127 > qbase) {   // wave-uniform; only the diagonal tile
      int qi = qbase + lrow;
#pragma unroll
      for (int nf = 0; nf < 8; ++nf) {
        int kbase = kt * 128 + nf * 16 + g * 4;
#pragma unroll
        for (int j = 0; j < 4; ++j)
          if (kbase + j > qi) sc[nf][j] = -1e30f;
      }
    }

    // row max: pairwise tree + 2 shuffles
    f32x4 v4 = sc[0];
#pragma unroll
    for (int nf = 1; nf < 8; ++nf)
#pragma unroll
      for (int j = 0; j < 4; ++j) v4[j] = fmaxf(v4[j], sc[nf][j]);
    float mx = redmax64(fmaxf(fmaxf(v4[0], v4[1]), fmaxf(v4[2], v4[3])));

    // defer-max (T13)
    bool nor = __all(mx <= m_ + 8.f);
    if (!nor) {
      float mnew = fmaxf(m_, mx);
      float al = exp2f(m_ - mnew);
      m_ = mnew;
      ls_ *= al;
#pragma unroll
      for (int nf = 0; nf < 4; ++nf)
#pragma unroll
        for (int j = 0; j < 4; ++j) O[nf][j] *= al;
    }

    // exp2 (row sum comes from the ones-MFMA below)
#pragma unroll
    for (int nf = 0; nf < 8; ++nf)
#pragma unroll
      for (int j = 0; j < 4; ++j) sc[nf][j] = exp2f(sc[nf][j] - m_);

    // PV in two 64-key halves through the wave-private P rows;
    // sacc accumulates the bf16-P row sum via mfma(ones, ap).
    f32x4 sacc = f32x4{0.f, 0.f, 0.f, 0.f};
#pragma unroll
    for (int half = 0; half < 2; ++half) {
      int prow = wrow + lrow;
#pragma unroll
      for (int nf2 = 0; nf2 < 4; ++nf2) {
        int nf = half * 4 + nf2;
        uint2 pk;
        pk.x = cvtpk(sc[nf][0], sc[nf][1]);
        pk.y = cvtpk(sc[nf][2], sc[nf][3]);
        *(uint2*)&Ps[swzK(prow, nf2 * 2 + (g >> 1)) + (g & 1) * 4] = pk;
      }
      __builtin_amdgcn_s_setprio(1);
#pragma unroll
      for (int ks2 = 0; ks2 < 2; ++ks2) {
        short8 ap = *(const short8*)&Ps[swzK(wrow + lrow, ks2 * 4 + g)];
        sacc = mfma_bf16(ones, ap, sacc);   // row sum, replicated in all regs
#pragma unroll
        for (int nf = 0; nf < 4; ++nf) {
          short8 bv = *(const short8*)&Vc[swzV(nf * 16 + lrow, half * 8 + ks2 * 4 + g)];
          O[nf] = mfma_bf16(bv, ap, O[nf]);
        }
      }
      __builtin_amdgcn_s_setprio(0);
    }
    ls_ += sacc[0];

    __syncthreads();   // staging drained; K/V ready for kt+1
  }

  // epilogue: lane q = wrow+lrow, d = nf*16 + g*4 + j
  float inv = 1.f / ls_;
  int srow = qt * 128 + wrow + lrow;
#pragma unroll
  for (int nf = 0; nf < 4; ++nf) {
    uint2 pk;
    pk.x = cvtpk(O[nf][0] * inv, O[nf][1] * inv);
    pk.y = cvtpk(O[nf][2] * inv, O[nf][3] * inv);
    *(uint2*)&ctx[((size_t)b * S_ + srow) * H_ + h * 64 + nf * 16 + g * 4] = pk;
  }
}

// ---------------------------------------------------------------- launch
extern "C" void kernel_launch(void* const* d_in, const int* in_sizes, int n_in,
                              void* d_out, int out_size, void* d_ws, size_t ws_size,
                              hipStream_t stream) {
  const float* x  = (const float*)d_in[0];
  const float* Wq = (const float*)d_in[1];
  const float* Wk = (const float*)d_in[2];
  const float* Wv = (const float*)d_in[3];
  const float* Wo = (const float*)d_in[4];

  char* ws = (char*)d_ws;
  size_t off = 0;
  ushort* xb   = (ushort*)(ws + off); off += (size_t)M_ * H_ * 2;
  ushort* Wqkv = (ushort*)(ws + off); off += (size_t)3 * H_ * H_ * 2;
  ushort* Wob  = (ushort*)(ws + off); off += (size_t)H_ * H_ * 2;
  float*  ct   = (float*)(ws + off);  off += (size_t)S_ * 32 * 4;
  float*  st   = (float*)(ws + off);  off += (size_t)S_ * 32 * 4;
  ushort* qb   = (ushort*)(ws + off); off += (size_t)M_ * H_ * 2;
  ushort* kb   = (ushort*)(ws + off); off += (size_t)M_ * H_ * 2;
  ushort* vtb  = (ushort*)(ws + off); off += (size_t)M_ * H_ * 2;
  ushort* ctx  = (ushort*)(ws + off); off += (size_t)M_ * H_ * 2;

  prep<<<8448, 256, 0, stream>>>(x, Wq, Wk, Wv, Wo, xb, Wqkv, Wob, ct, st);

  gemm_bt<2><<<dim3(3 * H_ / 128, M_ / 128), 256, 0, stream>>>(
      xb, Wqkv, nullptr, M_, 3 * H_, H_, ct, st, qb, kb, vtb);
  flash_attn<<<dim3(S_ / 128, B_ * NH_), 512, 0, stream>>>(qb, kb, vtb, ctx);
  gemm_bt<0><<<dim3(H_ / 128, M_ / 128), 256, 0, stream>>>(
      ctx, Wob, d_out, M_, H_, H_, nullptr, nullptr, nullptr, nullptr, nullptr);
}